// Round 1
// baseline (667.791 us; speedup 1.0000x reference)
//
#include <hip/hip_runtime.h>
#include <hip/hip_bf16.h>
#include <math.h>

#define NPIX 15376   // 124*124

__device__ __forceinline__ float bf_lo(unsigned u){ return __uint_as_float(u << 16); }
__device__ __forceinline__ float bf_hi(unsigned u){ return __uint_as_float(u & 0xffff0000u); }

// ---------------- K1: adaptive avg pool 126x126 -> 3x3 (42x42 blocks) ----------------
// grid = 8*64*9 = 4608 blocks, one output each. pooled layout [b][c][k], k=kh*3+kw.
__global__ __launch_bounds__(256) void k_pool(const float* __restrict__ x,
                                              float* __restrict__ pooled) {
  int bid = blockIdx.x;
  int k = bid % 9, c = (bid / 9) & 63, b = bid / 576;
  int kh = k / 3, kw = k % 3;
  const float* xp = x + ((size_t)(b * 64 + c) * 126 + kh * 42) * 126 + kw * 42;
  float s = 0.f;
  for (int i = threadIdx.x; i < 1764; i += 256)
    s += xp[(i / 42) * 126 + (i % 42)];
  #pragma unroll
  for (int off = 32; off; off >>= 1) s += __shfl_down(s, off);
  __shared__ float red[4];
  if ((threadIdx.x & 63) == 0) red[threadIdx.x >> 6] = s;
  __syncthreads();
  if (threadIdx.x == 0)
    pooled[bid] = (red[0] + red[1] + red[2] + red[3]) * (1.f / 1764.f);
}

// ---------------- K2: s1 = sigmoid(w1 @ pooled + b1), layout [b][o][k] ----------------
__global__ __launch_bounds__(256) void k_s1(const float* __restrict__ pooled,
                                            const float* __restrict__ w1,
                                            const float* __restrict__ b1,
                                            float* __restrict__ s1) {
  int idx = blockIdx.x * 256 + threadIdx.x;
  if (idx >= 4608) return;
  int k = idx % 9, o = (idx / 9) & 63, b = idx / 576;
  const float* pp = pooled + b * 576 + k;   // stride 9 per channel
  const float* wp = w1 + o * 64;
  float acc = b1[o];
  #pragma unroll 8
  for (int c = 0; c < 64; c++) acc += pp[c * 9] * wp[c];
  s1[idx] = 1.f / (1.f + expf(-acc));
}

// ---------------- K3: filter bank F[b][r][ci][k][co] (bf16) ----------------
// F(b,r,co,ci,k) = b2[r][co*64+ci] + sum_i s1[b][r*8+i][k] * w2[r][co*64+ci][i]
__global__ __launch_bounds__(256) void k_filters(const float* __restrict__ s1,
                                                 const float* __restrict__ w2,
                                                 const float* __restrict__ b2,
                                                 __hip_bfloat16* __restrict__ F) {
  int idx = blockIdx.x * 256 + threadIdx.x;   // 2,359,296 total, exact grid
  int co = idx & 63;
  int k  = (idx >> 6) % 9;
  int ci = (idx / 576) & 63;
  int r  = (idx / 36864) & 7;
  int b  = idx / 294912;
  int o = co * 64 + ci;
  const float* wp = w2 + (size_t)(r * 4096 + o) * 8;
  const float* sp = s1 + (b * 64 + r * 8) * 9 + k;   // stride 9 per i
  float acc = b2[r * 4096 + o];
  #pragma unroll
  for (int i = 0; i < 8; i++) acc += sp[i * 9] * wp[i];
  F[idx] = __float2bfloat16(acc);
}

// ---------------- K4: guide conv (f32) + argmax + per-(b,r) pixel list append --------
// grid = 256 blocks: b(8) x ty(8) x tx(4). Block tile 32 wide x 16 tall, 2 px/thread.
__global__ __launch_bounds__(256) void k_guide(const float* __restrict__ x,
                                               const float* __restrict__ wg,
                                               const float* __restrict__ bg,
                                               unsigned* __restrict__ counts,
                                               unsigned* __restrict__ lists) {
  __shared__ float wgl[4608];   // [ci][k][r]
  int t = threadIdx.x;
  for (int i = t; i < 4608; i += 256) {
    int r = i / 576, rem = i % 576;      // rem = ci*9+k
    wgl[rem * 8 + r] = wg[i];
  }
  __syncthreads();
  int bid = blockIdx.x;
  int tx = bid & 3, ty = (bid >> 2) & 7, b = bid >> 5;
  int x0 = tx * 32 + (t & 31);
  int y0 = ty * 16 + (t >> 5) * 2;
  int xc = min(x0, 123);
  int yc = min(y0, 122);                 // rows yc..yc+3 <= 125 stay in-bounds
  const float* xb = x + ((size_t)b * 64 * 126 + yc) * 126 + xc;
  float a0[8], a1[8];
  #pragma unroll
  for (int r = 0; r < 8; r++) { a0[r] = bg[r]; a1[r] = bg[r]; }
  for (int ci = 0; ci < 64; ci++) {
    const float* xp = xb + ci * 15876;
    const float* wp = wgl + ci * 72;
    #pragma unroll
    for (int k = 0; k < 9; k++) {
      int off = (k / 3) * 126 + (k % 3);
      float xv0 = xp[off];
      float xv1 = xp[off + 126];
      #pragma unroll
      for (int r = 0; r < 8; r++) {
        float wv = wp[k * 8 + r];
        a0[r] += xv0 * wv;
        a1[r] += xv1 * wv;
      }
    }
  }
  if (x0 < 124) {
    if (y0 < 124) {
      int best = 0; float bv = a0[0];
      #pragma unroll
      for (int r = 1; r < 8; r++) if (a0[r] > bv) { bv = a0[r]; best = r; }
      unsigned pos = atomicAdd(&counts[b * 8 + best], 1u);
      lists[(size_t)(b * 8 + best) * NPIX + pos] = (unsigned)((y0 << 16) | x0);
    }
    if (y0 + 1 < 124) {
      int best = 0; float bv = a1[0];
      #pragma unroll
      for (int r = 1; r < 8; r++) if (a1[r] > bv) { bv = a1[r]; best = r; }
      unsigned pos = atomicAdd(&counts[b * 8 + best], 1u);
      lists[(size_t)(b * 8 + best) * NPIX + pos] = (unsigned)(((y0 + 1) << 16) | x0);
    }
  }
}

// ---------------- K5: compacted selected-region conv ----------------
// grid (61, r=8, b=8). Block: 256 px of one (b,r) list, 64 co in 2 LDS half-passes.
// Thread: cogrp = t&3 (8 co within half), pxg = t>>2 (4 px each).
__global__ __launch_bounds__(256) void k_conv(const float* __restrict__ x,
                                              const __hip_bfloat16* __restrict__ F,
                                              const unsigned* __restrict__ counts,
                                              const unsigned* __restrict__ lists,
                                              float* __restrict__ out) {
  int T = blockIdx.x, r = blockIdx.y, b = blockIdx.z;
  unsigned cnt = counts[b * 8 + r];
  if ((unsigned)(T * 256) >= cnt) return;

  __shared__ uint4 Fl[2304];   // [ci][k][32co as bf16] = 36,864 B
  int t = threadIdx.x;
  int cogrp = t & 3;
  int pxg = t >> 2;

  const unsigned* Lp = lists + (size_t)(b * 8 + r) * NPIX;
  int py[4], px[4]; bool val[4];
  #pragma unroll
  for (int q = 0; q < 4; q++) {
    int p = T * 256 + pxg * 4 + q;
    val[q] = (unsigned)p < cnt;
    p = min(p, (int)cnt - 1);
    unsigned v = Lp[p];
    py[q] = v >> 16; px[q] = v & 0xffff;
  }
  const float* xbase = x + (size_t)b * 64 * 15876;
  float* ob = out + (size_t)b * 64 * NPIX;
  const uint4* srcU4 = (const uint4*)(F + (size_t)(b * 8 + r) * 36864);

  #pragma unroll
  for (int half = 0; half < 2; half++) {
    // stage 32 co (bf16) for all 64 ci x 9 k: 2304 uint4
    #pragma unroll
    for (int j = 0; j < 9; j++) {
      int l = t + j * 256;
      Fl[l] = srcU4[(l >> 2) * 8 + half * 4 + (l & 3)];
    }
    __syncthreads();

    float acc[4][8];
    #pragma unroll
    for (int q = 0; q < 4; q++)
      #pragma unroll
      for (int j = 0; j < 8; j++) acc[q][j] = 0.f;

    const float* xp0 = xbase + py[0] * 126 + px[0];
    const float* xp1 = xbase + py[1] * 126 + px[1];
    const float* xp2 = xbase + py[2] * 126 + px[2];
    const float* xp3 = xbase + py[3] * 126 + px[3];

    for (int ci = 0; ci < 64; ci++) {
      #pragma unroll
      for (int k = 0; k < 9; k++) {
        uint4 fu = Fl[ci * 36 + k * 4 + cogrp];
        float f[8];
        f[0] = bf_lo(fu.x); f[1] = bf_hi(fu.x);
        f[2] = bf_lo(fu.y); f[3] = bf_hi(fu.y);
        f[4] = bf_lo(fu.z); f[5] = bf_hi(fu.z);
        f[6] = bf_lo(fu.w); f[7] = bf_hi(fu.w);
        int off = (k / 3) * 126 + (k % 3);
        float xv0 = xp0[off], xv1 = xp1[off], xv2 = xp2[off], xv3 = xp3[off];
        #pragma unroll
        for (int j = 0; j < 8; j++) {
          acc[0][j] += xv0 * f[j];
          acc[1][j] += xv1 * f[j];
          acc[2][j] += xv2 * f[j];
          acc[3][j] += xv3 * f[j];
        }
      }
      xp0 += 15876; xp1 += 15876; xp2 += 15876; xp3 += 15876;
    }

    int co0 = half * 32 + cogrp * 8;
    #pragma unroll
    for (int q = 0; q < 4; q++) if (val[q]) {
      int p = py[q] * 124 + px[q];
      #pragma unroll
      for (int j = 0; j < 8; j++)
        ob[(size_t)(co0 + j) * NPIX + p] = acc[q][j];
    }
    __syncthreads();
  }
}

extern "C" void kernel_launch(void* const* d_in, const int* in_sizes, int n_in,
                              void* d_out, int out_size, void* d_ws, size_t ws_size,
                              hipStream_t stream) {
  (void)in_sizes; (void)n_in; (void)out_size; (void)ws_size;
  const float* x  = (const float*)d_in[0];
  const float* w1 = (const float*)d_in[1];
  const float* b1 = (const float*)d_in[2];
  const float* w2 = (const float*)d_in[3];
  const float* b2 = (const float*)d_in[4];
  const float* wg = (const float*)d_in[5];
  const float* bg = (const float*)d_in[6];
  float* out = (float*)d_out;
  char* ws = (char*)d_ws;

  unsigned* counts        = (unsigned*)(ws);                 // 256 B
  float* pooled           = (float*)(ws + 256);              // 18,432 B
  float* s1               = (float*)(ws + 18688);            // 18,432 B
  __hip_bfloat16* F       = (__hip_bfloat16*)(ws + 37120);   // 4,718,592 B
  unsigned* lists         = (unsigned*)(ws + 4755712);       // 3,936,256 B  (total ~8.7 MB)

  hipMemsetAsync(counts, 0, 256, stream);
  k_pool   <<<4608, 256, 0, stream>>>(x, pooled);
  k_s1     <<<18,   256, 0, stream>>>(pooled, w1, b1, s1);
  k_filters<<<9216, 256, 0, stream>>>(s1, w2, b2, F);
  k_guide  <<<256,  256, 0, stream>>>(x, wg, bg, counts, lists);
  k_conv   <<<dim3(61, 8, 8), 256, 0, stream>>>(x, F, counts, lists, out);
}

// Round 2
// 448.938 us; speedup vs baseline: 1.4875x; 1.4875x over previous
//
#include <hip/hip_runtime.h>
#include <hip/hip_fp16.h>
#include <math.h>

#define NPIX 15376   // 124*124

// ---------------- K0: transpose w2 -> w2t[r][i][ci*64+co], b2 -> b2t[r][ci*64+co] ----
__global__ __launch_bounds__(256) void k_prep(const float* __restrict__ w2,
                                              const float* __restrict__ b2,
                                              float* __restrict__ w2t,
                                              float* __restrict__ b2t) {
  int j = blockIdx.x * 256 + threadIdx.x;        // 262,144 exact
  int co = j & 63, ci = (j >> 6) & 63, i = (j >> 12) & 7, r = j >> 15;
  w2t[j] = w2[((size_t)r * 4096 + co * 64 + ci) * 8 + i];
  if (j < 32768) {
    int co2 = j & 63, ci2 = (j >> 6) & 63, r2 = j >> 12;
    b2t[j] = b2[r2 * 4096 + co2 * 64 + ci2];
  }
}

// ---------------- K1: adaptive avg pool 126x126 -> 3x3 (42x42 blocks) ----------------
__global__ __launch_bounds__(256) void k_pool(const float* __restrict__ x,
                                              float* __restrict__ pooled) {
  int bid = blockIdx.x;
  int k = bid % 9, c = (bid / 9) & 63, b = bid / 576;
  int kh = k / 3, kw = k % 3;
  const float* xp = x + ((size_t)(b * 64 + c) * 126 + kh * 42) * 126 + kw * 42;
  float s = 0.f;
  for (int i = threadIdx.x; i < 1764; i += 256)
    s += xp[(i / 42) * 126 + (i % 42)];
  #pragma unroll
  for (int off = 32; off; off >>= 1) s += __shfl_down(s, off);
  __shared__ float red[4];
  if ((threadIdx.x & 63) == 0) red[threadIdx.x >> 6] = s;
  __syncthreads();
  if (threadIdx.x == 0)
    pooled[bid] = (red[0] + red[1] + red[2] + red[3]) * (1.f / 1764.f);
}

// ---------------- K2: s1 = sigmoid(w1 @ pooled + b1), layout [b][o][k] ----------------
__global__ __launch_bounds__(256) void k_s1(const float* __restrict__ pooled,
                                            const float* __restrict__ w1,
                                            const float* __restrict__ b1,
                                            float* __restrict__ s1) {
  int idx = blockIdx.x * 256 + threadIdx.x;
  if (idx >= 4608) return;
  int k = idx % 9, o = (idx / 9) & 63, b = idx / 576;
  const float* pp = pooled + b * 576 + k;   // stride 9 per channel
  const float* wp = w1 + o * 64;
  float acc = b1[o];
  #pragma unroll 8
  for (int c = 0; c < 64; c++) acc += pp[c * 9] * wp[c];
  s1[idx] = 1.f / (1.f + expf(-acc));
}

// ---------------- K3: filter bank F2[(b,r,oct)][ci*9+k][co8] (f16) -------------------
// F(b,r,co,ci,k) = b2[r][o] + sum_i s1[b][r*8+i][k] * w2[r][o][i],  o = co*64+ci
__global__ __launch_bounds__(256) void k_filters(const float* __restrict__ s1,
                                                 const float* __restrict__ w2t,
                                                 const float* __restrict__ b2t,
                                                 __half* __restrict__ F2) {
  int idx = blockIdx.x * 256 + threadIdx.x;   // 2,359,296 exact
  int co8 = idx & 7;
  int k   = (idx >> 3) % 9;
  int ci  = (idx / 72) & 63;
  int oct = (idx / 4608) & 7;
  int r   = (idx / 36864) & 7;
  int b   = idx / 294912;
  int co = oct * 8 + co8;
  int op = ci * 64 + co;
  float acc = b2t[r * 4096 + op];
  const float* sp = s1 + (b * 64 + r * 8) * 9 + k;     // stride 9 per i
  const float* wp = w2t + (size_t)(r * 8) * 4096 + op; // stride 4096 per i
  #pragma unroll
  for (int i = 0; i < 8; i++) acc += sp[i * 9] * wp[(size_t)i * 4096];
  F2[idx] = __float2half(acc);
}

// ---------------- K4: guide conv (f32) + argmax -> rmap bytes ------------------------
__global__ __launch_bounds__(256) void k_guide(const float* __restrict__ x,
                                               const float* __restrict__ wg,
                                               const float* __restrict__ bg,
                                               unsigned char* __restrict__ rmap) {
  __shared__ float wgl[4608];   // [ci][k][r]
  int t = threadIdx.x;
  for (int i = t; i < 4608; i += 256) {
    int r = i / 576, rem = i % 576;      // rem = ci*9+k
    wgl[rem * 8 + r] = wg[i];
  }
  __syncthreads();
  int bid = blockIdx.x;
  int tx = bid & 3, ty = (bid >> 2) & 7, b = bid >> 5;
  int x0 = tx * 32 + (t & 31);
  int y0 = ty * 16 + (t >> 5) * 2;
  int xc = min(x0, 123);
  int yc = min(y0, 122);
  const float* xb = x + ((size_t)b * 64 * 126 + yc) * 126 + xc;
  float a0[8], a1[8];
  #pragma unroll
  for (int r = 0; r < 8; r++) { a0[r] = bg[r]; a1[r] = bg[r]; }
  for (int ci = 0; ci < 64; ci++) {
    const float* xp = xb + ci * 15876;
    const float* wp = wgl + ci * 72;
    #pragma unroll
    for (int k = 0; k < 9; k++) {
      int off = (k / 3) * 126 + (k % 3);
      float xv0 = xp[off];
      float xv1 = xp[off + 126];
      #pragma unroll
      for (int r = 0; r < 8; r++) {
        float wv = wp[k * 8 + r];
        a0[r] += xv0 * wv;
        a1[r] += xv1 * wv;
      }
    }
  }
  if (x0 < 124) {
    if (y0 < 124) {
      int best = 0; float bv = a0[0];
      #pragma unroll
      for (int r = 1; r < 8; r++) if (a0[r] > bv) { bv = a0[r]; best = r; }
      rmap[b * NPIX + y0 * 124 + x0] = (unsigned char)best;
    }
    if (y0 + 1 < 124) {
      int best = 0; float bv = a1[0];
      #pragma unroll
      for (int r = 1; r < 8; r++) if (a1[r] > bv) { bv = a1[r]; best = r; }
      rmap[b * NPIX + (y0 + 1) * 124 + x0] = (unsigned char)best;
    }
  }
}

// ---------------- K5: dense-tile selected-region conv --------------------------------
// Tile 32x16 output px, 512 threads (1 px/thread). LDS: x patch [64ci][18][34] f16
// (78,336 B) + all-8-region filters for one co-octet [8r][577 uint4] (73,856 B).
// Region-plane stride 577*16=9232 B == 4 banks offset per r -> conflict-free b128.
#define PATCH_HALFS 39168   // 64*612
#define FL_OFF      78336
#define SMEM_BYTES  152192  // 78336 + 8*577*16

__global__ __launch_bounds__(512, 1) void k_conv2(const float* __restrict__ x,
                                                  const __half* __restrict__ F2,
                                                  const unsigned char* __restrict__ rmap,
                                                  float* __restrict__ out) {
  extern __shared__ char smem[];
  __half* patch = (__half*)smem;              // [ci][row][col] stride 612/34
  uint4* Fl = (uint4*)(smem + FL_OFF);        // [r][577]

  int tx = blockIdx.x, ty = blockIdx.y, b = blockIdx.z;
  int x0 = tx * 32, y0 = ty * 16;
  int t = threadIdx.x;

  // ---- stage x patch (f32 -> f16), coalesced, edge-clamped ----
  for (int e = t; e < PATCH_HALFS; e += 512) {
    int ci = e / 612;
    int rem = e - ci * 612;
    int row = rem / 34;
    int col = rem - row * 34;
    int gy = min(y0 + row, 125);
    int gx = min(x0 + col, 125);
    patch[e] = __float2half(x[((size_t)(b * 64 + ci) * 126 + gy) * 126 + gx]);
  }

  int prow = t >> 5, pcol = t & 31;
  int gy = y0 + prow, gx = x0 + pcol;
  bool valid = (gy < 124) && (gx < 124);
  int rr = valid ? (int)rmap[b * NPIX + gy * 124 + gx] : 0;

  const uint4* F2u = (const uint4*)F2;
  const __half* xp0 = patch + prow * 34 + pcol;

  for (int oct = 0; oct < 8; ++oct) {
    __syncthreads();   // previous round's reads done before overwrite
    #pragma unroll
    for (int i = 0; i < 9; ++i) {
      int l = t + i * 512;
      int r = l / 576;
      int idx = l - r * 576;
      Fl[r * 577 + idx] = F2u[((size_t)(b * 8 + r)) * 4608 + oct * 576 + idx];
    }
    __syncthreads();

    float acc[8];
    #pragma unroll
    for (int j = 0; j < 8; ++j) acc[j] = 0.f;

    const uint4* fb = Fl + rr * 577;
    #pragma unroll 2
    for (int ci = 0; ci < 64; ++ci) {
      const __half* xp = xp0 + ci * 612;
      const uint4* fp = fb + ci * 9;
      #pragma unroll
      for (int k = 0; k < 9; ++k) {
        uint4 f = fp[k];
        float xv = __half2float(xp[(k / 3) * 34 + (k % 3)]);
        const __half2* hp = reinterpret_cast<const __half2*>(&f);
        float2 c0 = __half22float2(hp[0]);
        float2 c1 = __half22float2(hp[1]);
        float2 c2 = __half22float2(hp[2]);
        float2 c3 = __half22float2(hp[3]);
        acc[0] = fmaf(xv, c0.x, acc[0]);
        acc[1] = fmaf(xv, c0.y, acc[1]);
        acc[2] = fmaf(xv, c1.x, acc[2]);
        acc[3] = fmaf(xv, c1.y, acc[3]);
        acc[4] = fmaf(xv, c2.x, acc[4]);
        acc[5] = fmaf(xv, c2.y, acc[5]);
        acc[6] = fmaf(xv, c3.x, acc[6]);
        acc[7] = fmaf(xv, c3.y, acc[7]);
      }
    }

    if (valid) {
      size_t p = (size_t)gy * 124 + gx;
      float* op = out + ((size_t)(b * 64 + oct * 8)) * NPIX + p;
      #pragma unroll
      for (int j = 0; j < 8; ++j) op[(size_t)j * NPIX] = acc[j];
    }
  }
}

extern "C" void kernel_launch(void* const* d_in, const int* in_sizes, int n_in,
                              void* d_out, int out_size, void* d_ws, size_t ws_size,
                              hipStream_t stream) {
  (void)in_sizes; (void)n_in; (void)out_size; (void)ws_size;
  const float* x  = (const float*)d_in[0];
  const float* w1 = (const float*)d_in[1];
  const float* b1 = (const float*)d_in[2];
  const float* w2 = (const float*)d_in[3];
  const float* b2 = (const float*)d_in[4];
  const float* wg = (const float*)d_in[5];
  const float* bg = (const float*)d_in[6];
  float* out = (float*)d_out;
  char* ws = (char*)d_ws;

  __half* F2          = (__half*)(ws);                    // 4,718,592 B
  float* w2t          = (float*)(ws + 4718592);           // 1,048,576 B
  float* b2t          = (float*)(ws + 5767168);           //   131,072 B
  float* pooled       = (float*)(ws + 5898240);           //    18,432 B
  float* s1           = (float*)(ws + 5916672);           //    18,432 B
  unsigned char* rmap = (unsigned char*)(ws + 5935104);   //   123,008 B

  hipFuncSetAttribute((const void*)k_conv2,
                      hipFuncAttributeMaxDynamicSharedMemorySize, SMEM_BYTES);

  k_prep   <<<1024, 256, 0, stream>>>(w2, b2, w2t, b2t);
  k_pool   <<<4608, 256, 0, stream>>>(x, pooled);
  k_s1     <<<18,   256, 0, stream>>>(pooled, w1, b1, s1);
  k_filters<<<9216, 256, 0, stream>>>(s1, w2t, b2t, F2);
  k_guide  <<<256,  256, 0, stream>>>(x, wg, bg, rmap);
  k_conv2  <<<dim3(4, 8, 8), 512, SMEM_BYTES, stream>>>(x, F2, rmap, out);
}

// Round 3
// 248.225 us; speedup vs baseline: 2.6903x; 1.8086x over previous
//
#include <hip/hip_runtime.h>
#include <hip/hip_fp16.h>
#include <math.h>

#define NPIX 15376   // 124*124

typedef _Float16 h2 __attribute__((ext_vector_type(2)));

__device__ __forceinline__ h2 as_h2(unsigned u) {
  union { unsigned u; h2 h; } c; c.u = u; return c.h;
}

__device__ __forceinline__ float dot2(h2 a, h2 b, float c) {
#if __has_builtin(__builtin_amdgcn_fdot2)
  return __builtin_amdgcn_fdot2(a, b, c, false);
#else
  return fmaf((float)a.x, (float)b.x, fmaf((float)a.y, (float)b.y, c));
#endif
}

// ---------------- K0: transpose w2 -> w2t[r][i][ci*64+co], b2 -> b2t[r][ci*64+co] ----
__global__ __launch_bounds__(256) void k_prep(const float* __restrict__ w2,
                                              const float* __restrict__ b2,
                                              float* __restrict__ w2t,
                                              float* __restrict__ b2t) {
  int j = blockIdx.x * 256 + threadIdx.x;        // 262,144 exact
  int co = j & 63, ci = (j >> 6) & 63, i = (j >> 12) & 7, r = j >> 15;
  w2t[j] = w2[((size_t)r * 4096 + co * 64 + ci) * 8 + i];
  if (j < 32768) {
    int co2 = j & 63, ci2 = (j >> 6) & 63, r2 = j >> 12;
    b2t[j] = b2[r2 * 4096 + co2 * 64 + ci2];
  }
}

// ---------------- K1: adaptive avg pool 126x126 -> 3x3 (42x42 blocks) ----------------
__global__ __launch_bounds__(256) void k_pool(const float* __restrict__ x,
                                              float* __restrict__ pooled) {
  int bid = blockIdx.x;
  int k = bid % 9, c = (bid / 9) & 63, b = bid / 576;
  int kh = k / 3, kw = k % 3;
  const float* xp = x + ((size_t)(b * 64 + c) * 126 + kh * 42) * 126 + kw * 42;
  float s = 0.f;
  for (int i = threadIdx.x; i < 1764; i += 256)
    s += xp[(i / 42) * 126 + (i % 42)];
  #pragma unroll
  for (int off = 32; off; off >>= 1) s += __shfl_down(s, off);
  __shared__ float red[4];
  if ((threadIdx.x & 63) == 0) red[threadIdx.x >> 6] = s;
  __syncthreads();
  if (threadIdx.x == 0)
    pooled[bid] = (red[0] + red[1] + red[2] + red[3]) * (1.f / 1764.f);
}

// ---------------- K2: s1 = sigmoid(w1 @ pooled + b1), layout [b][o][k] ----------------
__global__ __launch_bounds__(256) void k_s1(const float* __restrict__ pooled,
                                            const float* __restrict__ w1,
                                            const float* __restrict__ b1,
                                            float* __restrict__ s1) {
  int idx = blockIdx.x * 256 + threadIdx.x;
  if (idx >= 4608) return;
  int k = idx % 9, o = (idx / 9) & 63, b = idx / 576;
  const float* pp = pooled + b * 576 + k;   // stride 9 per channel
  const float* wp = w1 + o * 64;
  float acc = b1[o];
  #pragma unroll 8
  for (int c = 0; c < 64; c++) acc += pp[c * 9] * wp[c];
  s1[idx] = 1.f / (1.f + expf(-acc));
}

// ---------------- K3: filter bank, half2-paired-over-ci layout ----------------------
// F2 halves: idx = ((((b*8+r)*8+oct)*9+k)*32+ci2)*16 + co8*2 + (ci&1)
// value = F(b,r, co=oct*8+co8, ci=ci2*2+ciL, k)
__global__ __launch_bounds__(256) void k_filters(const float* __restrict__ s1,
                                                 const float* __restrict__ w2t,
                                                 const float* __restrict__ b2t,
                                                 __half* __restrict__ F2) {
  int idx = blockIdx.x * 256 + threadIdx.x;   // 2,359,296 exact
  int low = idx & 15;
  int ciL = low & 1, co8 = low >> 1;
  int j = idx >> 4;
  int ci2 = j & 31; j >>= 5;
  int k = j % 9; j /= 9;
  int oct = j & 7;
  int r = (j >> 3) & 7;
  int b = j >> 6;
  int ci = ci2 * 2 + ciL;
  int co = oct * 8 + co8;
  int op = ci * 64 + co;
  float acc = b2t[r * 4096 + op];
  const float* sp = s1 + (b * 64 + r * 8) * 9 + k;     // stride 9 per i
  const float* wp = w2t + (size_t)(r * 8) * 4096 + op; // stride 4096 per i
  #pragma unroll
  for (int i = 0; i < 8; i++) acc += sp[i * 9] * wp[(size_t)i * 4096];
  F2[idx] = __float2half(acc);
}

// ---------------- K4: guide conv (f32) + argmax -> rmap bytes ------------------------
__global__ __launch_bounds__(256) void k_guide(const float* __restrict__ x,
                                               const float* __restrict__ wg,
                                               const float* __restrict__ bg,
                                               unsigned char* __restrict__ rmap) {
  __shared__ float wgl[4608];   // [ci][k][r]
  int t = threadIdx.x;
  for (int i = t; i < 4608; i += 256) {
    int r = i / 576, rem = i % 576;      // rem = ci*9+k
    wgl[rem * 8 + r] = wg[i];
  }
  __syncthreads();
  int bid = blockIdx.x;
  int tx = bid & 3, ty = (bid >> 2) & 7, b = bid >> 5;
  int x0 = tx * 32 + (t & 31);
  int y0 = ty * 16 + (t >> 5) * 2;
  int xc = min(x0, 123);
  int yc = min(y0, 122);
  const float* xb = x + ((size_t)b * 64 * 126 + yc) * 126 + xc;
  float a0[8], a1[8];
  #pragma unroll
  for (int r = 0; r < 8; r++) { a0[r] = bg[r]; a1[r] = bg[r]; }
  for (int ci = 0; ci < 64; ci++) {
    const float* xp = xb + ci * 15876;
    const float* wp = wgl + ci * 72;
    #pragma unroll
    for (int k = 0; k < 9; k++) {
      int off = (k / 3) * 126 + (k % 3);
      float xv0 = xp[off];
      float xv1 = xp[off + 126];
      #pragma unroll
      for (int r = 0; r < 8; r++) {
        float wv = wp[k * 8 + r];
        a0[r] += xv0 * wv;
        a1[r] += xv1 * wv;
      }
    }
  }
  if (x0 < 124) {
    if (y0 < 124) {
      int best = 0; float bv = a0[0];
      #pragma unroll
      for (int r = 1; r < 8; r++) if (a0[r] > bv) { bv = a0[r]; best = r; }
      rmap[b * NPIX + y0 * 124 + x0] = (unsigned char)best;
    }
    if (y0 + 1 < 124) {
      int best = 0; float bv = a1[0];
      #pragma unroll
      for (int r = 1; r < 8; r++) if (a1[r] > bv) { bv = a1[r]; best = r; }
      rmap[b * NPIX + (y0 + 1) * 124 + x0] = (unsigned char)best;
    }
  }
}

// ---------------- K5: dense-tile selected-region conv, v_dot2_f32_f16 ----------------
// Tile 32x16 output px, 512 threads (1 px/thread).
// LDS: x patch half2[32 ci2][18][34] (78,336 B) + filters for one co-octet,
//      all 8 regions: uint4[8 r][577] (73,856 B; plane stride 9232 B == +4 banks/r).
// Inner (ci2,k): 2x ds_read_b128 (8 co half2-pairs, same-region lanes broadcast)
//                + 1x ds_read_b32 (x pair) + 8x v_dot2_f32_f16.
#define PATCH_U32S 19584    // 32*612
#define FL_OFF     78336
#define SMEM_BYTES 152192   // 78336 + 8*577*16

__global__ __launch_bounds__(512, 1) void k_conv2(const float* __restrict__ x,
                                                  const __half* __restrict__ F2,
                                                  const unsigned char* __restrict__ rmap,
                                                  float* __restrict__ out) {
  extern __shared__ char smem[];
  unsigned* patch2 = (unsigned*)smem;          // [ci2][row][col], row stride 34
  uint4* Fl = (uint4*)(smem + FL_OFF);         // [r][577]

  int tx = blockIdx.x, ty = blockIdx.y, b = blockIdx.z;
  int x0 = tx * 32, y0 = ty * 16;
  int t = threadIdx.x;

  // ---- stage x patch as half2(ci even, ci odd), coalesced, edge-clamped ----
  for (int e = t; e < PATCH_U32S; e += 512) {
    int ci2 = e / 612;
    int rem = e - ci2 * 612;
    int row = rem / 34;
    int col = rem - row * 34;
    int gy = min(y0 + row, 125);
    int gx = min(x0 + col, 125);
    const float* xp = x + ((size_t)(b * 64 + ci2 * 2) * 126 + gy) * 126 + gx;
    unsigned lo = __half_as_ushort(__float2half(xp[0]));
    unsigned hi = __half_as_ushort(__float2half(xp[15876]));
    patch2[e] = (hi << 16) | lo;
  }

  int prow = t >> 5, pcol = t & 31;
  int gy = y0 + prow, gx = x0 + pcol;
  bool valid = (gy < 124) && (gx < 124);
  int rr = valid ? (int)rmap[b * NPIX + gy * 124 + gx] : 0;

  const uint4* F2g = (const uint4*)F2;         // 576 uint4 per (b,r,oct)
  const unsigned* xp0 = patch2 + prow * 34 + pcol;
  const uint4* fb_base = Fl + rr * 577;

  for (int oct = 0; oct < 8; ++oct) {
    __syncthreads();   // previous round's reads done before overwrite
    #pragma unroll
    for (int i = 0; i < 9; ++i) {
      int l = t + i * 512;
      int r = l / 576;
      int q = l - r * 576;
      Fl[r * 577 + q] = F2g[((size_t)((b * 8 + r) * 8 + oct)) * 576 + q];
    }
    __syncthreads();

    float acc[8];
    #pragma unroll
    for (int j = 0; j < 8; ++j) acc[j] = 0.f;

    #pragma unroll 2
    for (int ci2 = 0; ci2 < 32; ++ci2) {
      const unsigned* xp = xp0 + ci2 * 612;
      const uint4* fp = fb_base + ci2 * 2;
      #pragma unroll
      for (int k = 0; k < 9; ++k) {
        uint4 f0 = fp[k * 64];       // (k*32+ci2)*2
        uint4 f1 = fp[k * 64 + 1];
        h2 xv = as_h2(xp[(k / 3) * 34 + (k % 3)]);
        acc[0] = dot2(xv, as_h2(f0.x), acc[0]);
        acc[1] = dot2(xv, as_h2(f0.y), acc[1]);
        acc[2] = dot2(xv, as_h2(f0.z), acc[2]);
        acc[3] = dot2(xv, as_h2(f0.w), acc[3]);
        acc[4] = dot2(xv, as_h2(f1.x), acc[4]);
        acc[5] = dot2(xv, as_h2(f1.y), acc[5]);
        acc[6] = dot2(xv, as_h2(f1.z), acc[6]);
        acc[7] = dot2(xv, as_h2(f1.w), acc[7]);
      }
    }

    if (valid) {
      size_t p = (size_t)gy * 124 + gx;
      float* op = out + ((size_t)(b * 64 + oct * 8)) * NPIX + p;
      #pragma unroll
      for (int j = 0; j < 8; ++j) op[(size_t)j * NPIX] = acc[j];
    }
  }
}

extern "C" void kernel_launch(void* const* d_in, const int* in_sizes, int n_in,
                              void* d_out, int out_size, void* d_ws, size_t ws_size,
                              hipStream_t stream) {
  (void)in_sizes; (void)n_in; (void)out_size; (void)ws_size;
  const float* x  = (const float*)d_in[0];
  const float* w1 = (const float*)d_in[1];
  const float* b1 = (const float*)d_in[2];
  const float* w2 = (const float*)d_in[3];
  const float* b2 = (const float*)d_in[4];
  const float* wg = (const float*)d_in[5];
  const float* bg = (const float*)d_in[6];
  float* out = (float*)d_out;
  char* ws = (char*)d_ws;

  __half* F2          = (__half*)(ws);                    // 4,718,592 B
  float* w2t          = (float*)(ws + 4718592);           // 1,048,576 B
  float* b2t          = (float*)(ws + 5767168);           //   131,072 B
  float* pooled       = (float*)(ws + 5898240);           //    18,432 B
  float* s1           = (float*)(ws + 5916672);           //    18,432 B
  unsigned char* rmap = (unsigned char*)(ws + 5935104);   //   123,008 B

  hipFuncSetAttribute((const void*)k_conv2,
                      hipFuncAttributeMaxDynamicSharedMemorySize, SMEM_BYTES);

  k_prep   <<<1024, 256, 0, stream>>>(w2, b2, w2t, b2t);
  k_pool   <<<4608, 256, 0, stream>>>(x, pooled);
  k_s1     <<<18,   256, 0, stream>>>(pooled, w1, b1, s1);
  k_filters<<<9216, 256, 0, stream>>>(s1, w2t, b2t, F2);
  k_guide  <<<256,  256, 0, stream>>>(x, wg, bg, rmap);
  k_conv2  <<<dim3(4, 8, 8), 512, SMEM_BYTES, stream>>>(x, F2, rmap, out);
}

// Round 4
// 195.330 us; speedup vs baseline: 3.4188x; 1.2708x over previous
//
#include <hip/hip_runtime.h>
#include <hip/hip_fp16.h>
#include <math.h>

#define NPIX 15376   // 124*124

typedef _Float16 half8 __attribute__((ext_vector_type(8)));
typedef float f32x16 __attribute__((ext_vector_type(16)));

union Q2H { uint4 q; half8 h; };

// ---------------- K0: transpose w2 -> w2t[r][i][ci*64+co], b2 -> b2t[r][ci*64+co] ----
__global__ __launch_bounds__(256) void k_prep(const float* __restrict__ w2,
                                              const float* __restrict__ b2,
                                              float* __restrict__ w2t,
                                              float* __restrict__ b2t) {
  int j = blockIdx.x * 256 + threadIdx.x;        // 262,144 exact
  int co = j & 63, ci = (j >> 6) & 63, i = (j >> 12) & 7, r = j >> 15;
  w2t[j] = w2[((size_t)r * 4096 + co * 64 + ci) * 8 + i];
  if (j < 32768) {
    int co2 = j & 63, ci2 = (j >> 6) & 63, r2 = j >> 12;
    b2t[j] = b2[r2 * 4096 + co2 * 64 + ci2];
  }
}

// ---------------- K1: adaptive avg pool 126x126 -> 3x3 (42x42 blocks) ----------------
__global__ __launch_bounds__(256) void k_pool(const float* __restrict__ x,
                                              float* __restrict__ pooled) {
  int bid = blockIdx.x;
  int k = bid % 9, c = (bid / 9) & 63, b = bid / 576;
  int kh = k / 3, kw = k % 3;
  const float* xp = x + ((size_t)(b * 64 + c) * 126 + kh * 42) * 126 + kw * 42;
  float s = 0.f;
  for (int i = threadIdx.x; i < 1764; i += 256)
    s += xp[(i / 42) * 126 + (i % 42)];
  #pragma unroll
  for (int off = 32; off; off >>= 1) s += __shfl_down(s, off);
  __shared__ float red[4];
  if ((threadIdx.x & 63) == 0) red[threadIdx.x >> 6] = s;
  __syncthreads();
  if (threadIdx.x == 0)
    pooled[bid] = (red[0] + red[1] + red[2] + red[3]) * (1.f / 1764.f);
}

// ---------------- K2: s1 = sigmoid(w1 @ pooled + b1), layout [b][o][k] ----------------
__global__ __launch_bounds__(256) void k_s1(const float* __restrict__ pooled,
                                            const float* __restrict__ w1,
                                            const float* __restrict__ b1,
                                            float* __restrict__ s1) {
  int idx = blockIdx.x * 256 + threadIdx.x;
  if (idx >= 4608) return;
  int k = idx % 9, o = (idx / 9) & 63, b = idx / 576;
  const float* pp = pooled + b * 576 + k;   // stride 9 per channel
  const float* wp = w1 + o * 64;
  float acc = b1[o];
  #pragma unroll 8
  for (int c = 0; c < 64; c++) acc += pp[c * 9] * wp[c];
  s1[idx] = 1.f / (1.f + expf(-acc));
}

// ---------------- K3: filter bank in MFMA B-fragment order ---------------------------
// F2 as uint4: idx = ((b*8+r)*72 + f)*64 + lane, f = kk*8 + slice*2 + cotile.
// Lane's 8 halves e=0..7: value F(b,r, co=cotile*32+(lane&31), ci=slice*16+(lane>>5)*8+e, kk)
__global__ __launch_bounds__(256) void k_filters(const float* __restrict__ s1,
                                                 const float* __restrict__ w2t,
                                                 const float* __restrict__ b2t,
                                                 __half* __restrict__ F2) {
  int idx = blockIdx.x * 256 + threadIdx.x;   // 294,912 exact (1152 blocks)
  int lane = idx & 63;
  int f = (idx >> 6) % 72;
  int r = (idx / 4608) & 7;
  int b = idx / 36864;
  int cotile = f & 1, slice = (f >> 1) & 3, kk = f >> 3;
  int co = cotile * 32 + (lane & 31);
  int ci0 = slice * 16 + (lane >> 5) * 8;
  float sv[8];
  #pragma unroll
  for (int i = 0; i < 8; i++) sv[i] = s1[(b * 64 + r * 8 + i) * 9 + kk];
  unsigned h[8];
  #pragma unroll
  for (int e = 0; e < 8; e++) {
    int op = (ci0 + e) * 64 + co;
    float acc = b2t[r * 4096 + op];
    #pragma unroll
    for (int i = 0; i < 8; i++) acc += sv[i] * w2t[(size_t)(r * 8 + i) * 4096 + op];
    h[e] = __half_as_ushort(__float2half(acc));
  }
  uint4 q;
  q.x = h[0] | (h[1] << 16);
  q.y = h[2] | (h[3] << 16);
  q.z = h[4] | (h[5] << 16);
  q.w = h[6] | (h[7] << 16);
  ((uint4*)F2)[idx] = q;
}

// ---------------- K4: guide conv (f32) + argmax -> rmap bytes ------------------------
__global__ __launch_bounds__(256) void k_guide(const float* __restrict__ x,
                                               const float* __restrict__ wg,
                                               const float* __restrict__ bg,
                                               unsigned char* __restrict__ rmap) {
  __shared__ float wgl[4608];   // [ci][k][r]
  int t = threadIdx.x;
  for (int i = t; i < 4608; i += 256) {
    int r = i / 576, rem = i % 576;      // rem = ci*9+k
    wgl[rem * 8 + r] = wg[i];
  }
  __syncthreads();
  int bid = blockIdx.x;
  int tx = bid & 3, ty = (bid >> 2) & 7, b = bid >> 5;
  int x0 = tx * 32 + (t & 31);
  int y0 = ty * 16 + (t >> 5) * 2;
  int xc = min(x0, 123);
  int yc = min(y0, 122);
  const float* xb = x + ((size_t)b * 64 * 126 + yc) * 126 + xc;
  float a0[8], a1[8];
  #pragma unroll
  for (int r = 0; r < 8; r++) { a0[r] = bg[r]; a1[r] = bg[r]; }
  for (int ci = 0; ci < 64; ci++) {
    const float* xp = xb + ci * 15876;
    const float* wp = wgl + ci * 72;
    #pragma unroll
    for (int k = 0; k < 9; k++) {
      int off = (k / 3) * 126 + (k % 3);
      float xv0 = xp[off];
      float xv1 = xp[off + 126];
      #pragma unroll
      for (int r = 0; r < 8; r++) {
        float wv = wp[k * 8 + r];
        a0[r] += xv0 * wv;
        a1[r] += xv1 * wv;
      }
    }
  }
  if (x0 < 124) {
    if (y0 < 124) {
      int best = 0; float bv = a0[0];
      #pragma unroll
      for (int r = 1; r < 8; r++) if (a0[r] > bv) { bv = a0[r]; best = r; }
      rmap[b * NPIX + y0 * 124 + x0] = (unsigned char)best;
    }
    if (y0 + 1 < 124) {
      int best = 0; float bv = a1[0];
      #pragma unroll
      for (int r = 1; r < 8; r++) if (a1[r] > bv) { bv = a1[r]; best = r; }
      rmap[b * NPIX + (y0 + 1) * 124 + x0] = (unsigned char)best;
    }
  }
}

// ---------------- K5: MFMA region conv ----------------------------------------------
// Block = 32x16 px tile, 512 threads. LDS: x patch channel-last f16 [18row][34col][64ci]
// with per-pixel XOR swizzle (byte ^= (pix&7)<<4 on the ci offset); per-region pixel
// lists; chunk worklist. Chunks of 32 same-region px -> 72x mfma_f32_32x32x16_f16
// (A from LDS b128, B from global L2-resident fragment-ordered F2).
#define PATCH_U32S 19584    // 612 pix * 32 ci-pairs
#define LIST_OFF   78336    // u16[8*512]
#define CNT_OFF    86528    // u32[8]
#define WL_OFF     86560    // u8[40]
#define WLT_OFF    86600    // u32
#define SMEM3      86656

__global__ __launch_bounds__(512, 1) void k_conv3(const float* __restrict__ x,
                                                  const __half* __restrict__ F2,
                                                  const unsigned char* __restrict__ rmap,
                                                  float* __restrict__ out) {
  extern __shared__ __align__(16) char smem[];
  unsigned short* list = (unsigned short*)(smem + LIST_OFF);
  unsigned* cnt = (unsigned*)(smem + CNT_OFF);
  unsigned char* wl = (unsigned char*)(smem + WL_OFF);
  unsigned* wltot = (unsigned*)(smem + WLT_OFF);

  int tx = blockIdx.x, ty = blockIdx.y, b = blockIdx.z;
  int x0 = tx * 32, y0 = ty * 16;
  int t = threadIdx.x;

  if (t < 8) cnt[t] = 0;

  // ---- stage x patch: channel-last f16, XOR-swizzled, coalesced global reads ----
  for (int e = t; e < PATCH_U32S; e += 512) {
    int ci2 = e / 612;
    int pix = e - ci2 * 612;
    int row = pix / 34, col = pix - row * 34;
    int gy = min(y0 + row, 125);
    int gx = min(x0 + col, 125);
    const float* xp = x + ((size_t)(b * 64 + ci2 * 2) * 126 + gy) * 126 + gx;
    unsigned lo = __half_as_ushort(__float2half(xp[0]));
    unsigned hi = __half_as_ushort(__float2half(xp[15876]));
    int byte = pix * 128 + ((ci2 * 4) ^ ((pix & 7) << 4));
    *(unsigned*)(smem + byte) = (hi << 16) | lo;
  }
  __syncthreads();   // patch staged, cnt zeroed

  // ---- per-region pixel lists (LDS atomics) ----
  {
    int prow = t >> 5, pcol = t & 31;
    int gy = y0 + prow, gx = x0 + pcol;
    if (gy < 124 && gx < 124) {
      int rr = rmap[b * NPIX + gy * 124 + gx];
      unsigned pos = atomicAdd(&cnt[rr], 1u);
      list[rr * 512 + pos] = (unsigned short)t;
    }
  }
  __syncthreads();

  if (t == 0) {
    int tot = 0;
    for (int r = 0; r < 8; r++) {
      int nc = ((int)cnt[r] + 31) >> 5;
      for (int j = 0; j < nc; j++) wl[tot++] = (unsigned char)((r << 4) | j);
    }
    *wltot = (unsigned)tot;
  }
  __syncthreads();

  int wid = t >> 6;
  int lane = t & 63;
  int l31 = lane & 31, lhi = lane >> 5;
  int nch = (int)*wltot;
  const uint4* F2q = (const uint4*)F2;

  for (int c = wid; c < nch; c += 8) {
    int wle = wl[c];
    int r = wle >> 4, slot = wle & 15;
    int rcnt = (int)cnt[r];
    int sidx = slot * 32 + l31;
    int ppos = list[r * 512 + min(sidx, rcnt - 1)];
    int prow = ppos >> 5, pcol = ppos & 31;
    const uint4* Fb = F2q + (size_t)(b * 8 + r) * 4608 + lane;

    f32x16 C0 = {0,0,0,0,0,0,0,0,0,0,0,0,0,0,0,0};
    f32x16 C1 = {0,0,0,0,0,0,0,0,0,0,0,0,0,0,0,0};

    #pragma unroll
    for (int kk = 0; kk < 9; kk++) {
      int pix = (prow + kk / 3) * 34 + pcol + (kk % 3);
      int pb = pix * 128;
      int sw = (pix & 7) << 4;
      // A fragments, 4 ci-slices (b128 each)
      half8 a0 = *(const half8*)(smem + pb + ((0  + lhi * 16) ^ sw));
      half8 a1 = *(const half8*)(smem + pb + ((32 + lhi * 16) ^ sw));
      half8 a2 = *(const half8*)(smem + pb + ((64 + lhi * 16) ^ sw));
      half8 a3 = *(const half8*)(smem + pb + ((96 + lhi * 16) ^ sw));
      // B fragments, 4 slices x 2 cotiles (global, L2-resident)
      const uint4* fk = Fb + (size_t)kk * 512;
      Q2H b00, b01, b10, b11, b20, b21, b30, b31;
      b00.q = fk[0];   b01.q = fk[64];
      b10.q = fk[128]; b11.q = fk[192];
      b20.q = fk[256]; b21.q = fk[320];
      b30.q = fk[384]; b31.q = fk[448];
      C0 = __builtin_amdgcn_mfma_f32_32x32x16_f16(a0, b00.h, C0, 0, 0, 0);
      C1 = __builtin_amdgcn_mfma_f32_32x32x16_f16(a0, b01.h, C1, 0, 0, 0);
      C0 = __builtin_amdgcn_mfma_f32_32x32x16_f16(a1, b10.h, C0, 0, 0, 0);
      C1 = __builtin_amdgcn_mfma_f32_32x32x16_f16(a1, b11.h, C1, 0, 0, 0);
      C0 = __builtin_amdgcn_mfma_f32_32x32x16_f16(a2, b20.h, C0, 0, 0, 0);
      C1 = __builtin_amdgcn_mfma_f32_32x32x16_f16(a2, b21.h, C1, 0, 0, 0);
      C0 = __builtin_amdgcn_mfma_f32_32x32x16_f16(a3, b30.h, C0, 0, 0, 0);
      C1 = __builtin_amdgcn_mfma_f32_32x32x16_f16(a3, b31.h, C1, 0, 0, 0);
    }

    // ---- epilogue: scatter C to out (lines L2-combine within block lifetime) ----
    float* ob = out + (size_t)b * 64 * NPIX;
    #pragma unroll
    for (int reg = 0; reg < 16; reg++) {
      int row = (reg & 3) + 8 * (reg >> 2) + 4 * lhi;
      int si = slot * 32 + row;
      if (si < rcnt) {
        int pp = list[r * 512 + si];
        size_t p = (size_t)(y0 + (pp >> 5)) * 124 + x0 + (pp & 31);
        ob[(size_t)l31 * NPIX + p] = C0[reg];
        ob[(size_t)(32 + l31) * NPIX + p] = C1[reg];
      }
    }
  }
}

extern "C" void kernel_launch(void* const* d_in, const int* in_sizes, int n_in,
                              void* d_out, int out_size, void* d_ws, size_t ws_size,
                              hipStream_t stream) {
  (void)in_sizes; (void)n_in; (void)out_size; (void)ws_size;
  const float* x  = (const float*)d_in[0];
  const float* w1 = (const float*)d_in[1];
  const float* b1 = (const float*)d_in[2];
  const float* w2 = (const float*)d_in[3];
  const float* b2 = (const float*)d_in[4];
  const float* wg = (const float*)d_in[5];
  const float* bg = (const float*)d_in[6];
  float* out = (float*)d_out;
  char* ws = (char*)d_ws;

  __half* F2          = (__half*)(ws);                    // 4,718,592 B
  float* w2t          = (float*)(ws + 4718592);           // 1,048,576 B
  float* b2t          = (float*)(ws + 5767168);           //   131,072 B
  float* pooled       = (float*)(ws + 5898240);           //    18,432 B
  float* s1           = (float*)(ws + 5916672);           //    18,432 B
  unsigned char* rmap = (unsigned char*)(ws + 5935104);   //   123,008 B

  hipFuncSetAttribute((const void*)k_conv3,
                      hipFuncAttributeMaxDynamicSharedMemorySize, SMEM3);

  k_prep   <<<1024, 256, 0, stream>>>(w2, b2, w2t, b2t);
  k_pool   <<<4608, 256, 0, stream>>>(x, pooled);
  k_s1     <<<18,   256, 0, stream>>>(pooled, w1, b1, s1);
  k_filters<<<1152, 256, 0, stream>>>(s1, w2t, b2t, F2);
  k_guide  <<<256,  256, 0, stream>>>(x, wg, bg, rmap);
  k_conv3  <<<dim3(4, 8, 8), 512, SMEM3, stream>>>(x, F2, rmap, out);
}

// Round 6
// 118.689 us; speedup vs baseline: 5.6264x; 1.6457x over previous
//
#include <hip/hip_runtime.h>
#include <hip/hip_fp16.h>
#include <math.h>

#define NPIX 15376   // 124*124

typedef _Float16 half8 __attribute__((ext_vector_type(8)));
typedef __fp16 fp16x2 __attribute__((ext_vector_type(2)));
typedef float f32x16 __attribute__((ext_vector_type(16)));

union Q2H { uint4 q; half8 h; };
union PK  { fp16x2 h; unsigned u; };
union UPK { uint2 q; _Float16 h[4]; };

// ---------------- K0: transpose w2 -> w2t[r][i][ci*64+co], b2 -> b2t[r][ci*64+co] ----
__global__ __launch_bounds__(256) void k_prep(const float* __restrict__ w2,
                                              const float* __restrict__ b2,
                                              float* __restrict__ w2t,
                                              float* __restrict__ b2t) {
  int j = blockIdx.x * 256 + threadIdx.x;        // 262,144 exact
  int co = j & 63, ci = (j >> 6) & 63, i = (j >> 12) & 7, r = j >> 15;
  w2t[j] = w2[((size_t)r * 4096 + co * 64 + ci) * 8 + i];
  if (j < 32768) {
    int co2 = j & 63, ci2 = (j >> 6) & 63, r2 = j >> 12;
    b2t[j] = b2[r2 * 4096 + co2 * 64 + ci2];
  }
}

// ---------------- K1: adaptive avg pool 126x126 -> 3x3 (42x42 blocks) ----------------
__global__ __launch_bounds__(256) void k_pool(const float* __restrict__ x,
                                              float* __restrict__ pooled) {
  int bid = blockIdx.x;
  int k = bid % 9, c = (bid / 9) & 63, b = bid / 576;
  int kh = k / 3, kw = k % 3;
  const float* xp = x + ((size_t)(b * 64 + c) * 126 + kh * 42) * 126 + kw * 42;
  float s = 0.f;
  for (int i = threadIdx.x; i < 1764; i += 256)
    s += xp[(i / 42) * 126 + (i % 42)];
  #pragma unroll
  for (int off = 32; off; off >>= 1) s += __shfl_down(s, off);
  __shared__ float red[4];
  if ((threadIdx.x & 63) == 0) red[threadIdx.x >> 6] = s;
  __syncthreads();
  if (threadIdx.x == 0)
    pooled[bid] = (red[0] + red[1] + red[2] + red[3]) * (1.f / 1764.f);
}

// ---------------- K2: s1 = sigmoid(w1 @ pooled + b1), layout [b][o][k] ----------------
__global__ __launch_bounds__(256) void k_s1(const float* __restrict__ pooled,
                                            const float* __restrict__ w1,
                                            const float* __restrict__ b1,
                                            float* __restrict__ s1) {
  int idx = blockIdx.x * 256 + threadIdx.x;
  if (idx >= 4608) return;
  int k = idx % 9, o = (idx / 9) & 63, b = idx / 576;
  const float* pp = pooled + b * 576 + k;   // stride 9 per channel
  const float* wp = w1 + o * 64;
  float acc = b1[o];
  #pragma unroll 8
  for (int c = 0; c < 64; c++) acc += pp[c * 9] * wp[c];
  s1[idx] = 1.f / (1.f + expf(-acc));
}

// ---------------- K3: filter bank in MFMA B-fragment order ---------------------------
// F2 as uint4: idx = ((b*8+r)*72 + f)*64 + lane, f = kk*8 + slice*2 + cotile.
// Lane's 8 halves e=0..7: value F(b,r, co=cotile*32+(lane&31), ci=slice*16+(lane>>5)*8+e, kk)
__global__ __launch_bounds__(256) void k_filters(const float* __restrict__ s1,
                                                 const float* __restrict__ w2t,
                                                 const float* __restrict__ b2t,
                                                 __half* __restrict__ F2) {
  int idx = blockIdx.x * 256 + threadIdx.x;   // 294,912 exact (1152 blocks)
  int lane = idx & 63;
  int f = (idx >> 6) % 72;
  int r = (idx / 4608) & 7;
  int b = idx / 36864;
  int cotile = f & 1, slice = (f >> 1) & 3, kk = f >> 3;
  int co = cotile * 32 + (lane & 31);
  int ci0 = slice * 16 + (lane >> 5) * 8;
  float sv[8];
  #pragma unroll
  for (int i = 0; i < 8; i++) sv[i] = s1[(b * 64 + r * 8 + i) * 9 + kk];
  unsigned h[8];
  #pragma unroll
  for (int e = 0; e < 8; e++) {
    int op = (ci0 + e) * 64 + co;
    float acc = b2t[r * 4096 + op];
    #pragma unroll
    for (int i = 0; i < 8; i++) acc += sv[i] * w2t[(size_t)(r * 8 + i) * 4096 + op];
    h[e] = __half_as_ushort(__float2half(acc));
  }
  uint4 q;
  q.x = h[0] | (h[1] << 16);
  q.y = h[2] | (h[3] << 16);
  q.z = h[4] | (h[5] << 16);
  q.w = h[6] | (h[7] << 16);
  ((uint4*)F2)[idx] = q;
}

// ---------------- K4: guide conv (f32) + argmax -> rmap bytes ------------------------
// 512 blocks (16x16 px tiles), 1 px/thread -> 2 blocks/CU for latency hiding.
__global__ __launch_bounds__(256) void k_guide(const float* __restrict__ x,
                                               const float* __restrict__ wg,
                                               const float* __restrict__ bg,
                                               unsigned char* __restrict__ rmap) {
  __shared__ float wgl[4608];   // [ci][k][r]
  int t = threadIdx.x;
  for (int i = t; i < 4608; i += 256) {
    int r = i / 576, rem = i % 576;      // rem = ci*9+k
    wgl[rem * 8 + r] = wg[i];
  }
  __syncthreads();
  int tx = blockIdx.x, ty = blockIdx.y, b = blockIdx.z;
  int gx = tx * 16 + (t & 15);
  int gy = ty * 16 + (t >> 4);
  int xc = min(gx, 123);
  int yc = min(gy, 123);
  const float* xb = x + ((size_t)b * 64 * 126 + yc) * 126 + xc;
  float a0[8];
  #pragma unroll
  for (int r = 0; r < 8; r++) a0[r] = bg[r];
  for (int ci = 0; ci < 64; ci++) {
    const float* xp = xb + ci * 15876;
    const float* wp = wgl + ci * 72;
    #pragma unroll
    for (int k = 0; k < 9; k++) {
      float xv = xp[(k / 3) * 126 + (k % 3)];
      #pragma unroll
      for (int r = 0; r < 8; r++) a0[r] += xv * wp[k * 8 + r];
    }
  }
  if (gx < 124 && gy < 124) {
    int best = 0; float bv = a0[0];
    #pragma unroll
    for (int r = 1; r < 8; r++) if (a0[r] > bv) { bv = a0[r]; best = r; }
    rmap[b * NPIX + gy * 124 + gx] = (unsigned char)best;
  }
}

// ---------------- K5: MFMA region conv, LDS-staged coalesced epilogue ----------------
// Block = 32x16 px tile, 512 threads. LDS: x patch channel-last f16 (XOR-swizzled) +
// C-buffer u32[32 co-pair][514] (pad->conflict-free) + per-region lists + worklist.
// Chunks of 32 same-region px -> 72x mfma_f32_32x32x16_f16; C packed f16x2 into cbuf;
// final pass writes out as dwordx2, 128B-contiguous per co.
#define PATCH_U32S 19584    // 612 pix * 32 ci-pairs
#define CBUF_OFF   78336    // u32[32][514] = 65,792 B
#define LIST_OFF   144128   // u16[8*512]   =  8,192 B
#define CNT_OFF    152320   // u32[8]
#define WL_OFF     152352   // u8[40]
#define WLT_OFF    152392   // u32
#define SMEM3      152400

__global__ __launch_bounds__(512, 1) void k_conv3(const float* __restrict__ x,
                                                  const __half* __restrict__ F2,
                                                  const unsigned char* __restrict__ rmap,
                                                  float* __restrict__ out) {
  extern __shared__ __align__(16) char smem[];
  unsigned* cbuf = (unsigned*)(smem + CBUF_OFF);
  unsigned short* list = (unsigned short*)(smem + LIST_OFF);
  unsigned* cnt = (unsigned*)(smem + CNT_OFF);
  unsigned char* wl = (unsigned char*)(smem + WL_OFF);
  unsigned* wltot = (unsigned*)(smem + WLT_OFF);

  int tx = blockIdx.x, ty = blockIdx.y, b = blockIdx.z;
  int x0 = tx * 32, y0 = ty * 16;
  int t = threadIdx.x;

  if (t < 8) cnt[t] = 0;

  // ---- stage x patch: channel-last f16, XOR-swizzled, coalesced global reads ----
  for (int e = t; e < PATCH_U32S; e += 512) {
    int ci2 = e / 612;
    int pix = e - ci2 * 612;
    int row = pix / 34, col = pix - row * 34;
    int gy = min(y0 + row, 125);
    int gx = min(x0 + col, 125);
    const float* xp = x + ((size_t)(b * 64 + ci2 * 2) * 126 + gy) * 126 + gx;
    unsigned lo = __half_as_ushort(__float2half(xp[0]));
    unsigned hi = __half_as_ushort(__float2half(xp[15876]));
    int byte = pix * 128 + ((ci2 * 4) ^ ((pix & 7) << 4));
    *(unsigned*)(smem + byte) = (hi << 16) | lo;
  }
  __syncthreads();   // patch staged, cnt zeroed

  // ---- per-region pixel lists (LDS atomics) ----
  {
    int prow = t >> 5, pcol = t & 31;
    int gy = y0 + prow, gx = x0 + pcol;
    if (gy < 124 && gx < 124) {
      int rr = rmap[b * NPIX + gy * 124 + gx];
      unsigned pos = atomicAdd(&cnt[rr], 1u);
      list[rr * 512 + pos] = (unsigned short)t;
    }
  }
  __syncthreads();

  if (t == 0) {
    int tot = 0;
    for (int r = 0; r < 8; r++) {
      int nc = ((int)cnt[r] + 31) >> 5;
      for (int j = 0; j < nc; j++) wl[tot++] = (unsigned char)((r << 4) | j);
    }
    *wltot = (unsigned)tot;
  }
  __syncthreads();

  int wid = t >> 6;
  int lane = t & 63;
  int l31 = lane & 31, lhi = lane >> 5;
  int nch = (int)*wltot;
  const uint4* F2q = (const uint4*)F2;

  for (int c = wid; c < nch; c += 8) {
    int wle = wl[c];
    int r = wle >> 4, slot = wle & 15;
    int rcnt = (int)cnt[r];
    int sidx = slot * 32 + l31;
    int ppos = list[r * 512 + min(sidx, rcnt - 1)];
    int prow = ppos >> 5, pcol = ppos & 31;
    const uint4* Fb = F2q + (size_t)(b * 8 + r) * 4608 + lane;

    f32x16 C0 = {0,0,0,0,0,0,0,0,0,0,0,0,0,0,0,0};
    f32x16 C1 = {0,0,0,0,0,0,0,0,0,0,0,0,0,0,0,0};

    #pragma unroll
    for (int kk = 0; kk < 9; kk++) {
      int pix = (prow + kk / 3) * 34 + pcol + (kk % 3);
      int pb = pix * 128;
      int sw = (pix & 7) << 4;
      // A fragments, 4 ci-slices (b128 each)
      half8 a0 = *(const half8*)(smem + pb + ((0  + lhi * 16) ^ sw));
      half8 a1 = *(const half8*)(smem + pb + ((32 + lhi * 16) ^ sw));
      half8 a2 = *(const half8*)(smem + pb + ((64 + lhi * 16) ^ sw));
      half8 a3 = *(const half8*)(smem + pb + ((96 + lhi * 16) ^ sw));
      // B fragments, 4 slices x 2 cotiles (global, L2-resident)
      const uint4* fk = Fb + (size_t)kk * 512;
      Q2H b00, b01, b10, b11, b20, b21, b30, b31;
      b00.q = fk[0];   b01.q = fk[64];
      b10.q = fk[128]; b11.q = fk[192];
      b20.q = fk[256]; b21.q = fk[320];
      b30.q = fk[384]; b31.q = fk[448];
      C0 = __builtin_amdgcn_mfma_f32_32x32x16_f16(a0, b00.h, C0, 0, 0, 0);
      C1 = __builtin_amdgcn_mfma_f32_32x32x16_f16(a0, b01.h, C1, 0, 0, 0);
      C0 = __builtin_amdgcn_mfma_f32_32x32x16_f16(a1, b10.h, C0, 0, 0, 0);
      C1 = __builtin_amdgcn_mfma_f32_32x32x16_f16(a1, b11.h, C1, 0, 0, 0);
      C0 = __builtin_amdgcn_mfma_f32_32x32x16_f16(a2, b20.h, C0, 0, 0, 0);
      C1 = __builtin_amdgcn_mfma_f32_32x32x16_f16(a2, b21.h, C1, 0, 0, 0);
      C0 = __builtin_amdgcn_mfma_f32_32x32x16_f16(a3, b30.h, C0, 0, 0, 0);
      C1 = __builtin_amdgcn_mfma_f32_32x32x16_f16(a3, b31.h, C1, 0, 0, 0);
    }

    // ---- pack (co, co+32) as f16x2 into cbuf[l31][pp] (stride 514 -> no conflict) ----
    #pragma unroll
    for (int reg = 0; reg < 16; reg++) {
      int row = (reg & 3) + 8 * (reg >> 2) + 4 * lhi;
      int si = slot * 32 + row;
      if (si < rcnt) {
        int pp = list[r * 512 + si];
        PK pk;
        pk.h = __builtin_amdgcn_cvt_pkrtz(C0[reg], C1[reg]);
        cbuf[l31 * 514 + pp] = pk.u;
      }
    }
  }
  __syncthreads();   // all chunks done, cbuf complete

  // ---- final pass: coalesced dwordx2 stores, pixel pairs ----
  {
    int half16 = t >> 8;              // cp block: 0 -> 0..15, 1 -> 16..31
    int pe = (t & 255) * 2;           // even pixel index
    int prow = pe >> 5, pcol = pe & 31;
    int gy = y0 + prow, gx = x0 + pcol;
    if (gy < 124 && gx < 124) {       // gx even => gx+1 also valid
      float* ob = out + (size_t)b * 64 * NPIX + (size_t)gy * 124 + gx;
      #pragma unroll
      for (int j = 0; j < 16; j++) {
        int cp = half16 * 16 + j;
        UPK c;
        c.q = *(const uint2*)&cbuf[cp * 514 + pe];
        float2 s0 = { (float)c.h[0], (float)c.h[2] };   // co=cp,    px pe, pe+1
        float2 s1 = { (float)c.h[1], (float)c.h[3] };   // co=cp+32, px pe, pe+1
        *(float2*)(ob + (size_t)cp * NPIX) = s0;
        *(float2*)(ob + (size_t)(cp + 32) * NPIX) = s1;
      }
    }
  }
}

extern "C" void kernel_launch(void* const* d_in, const int* in_sizes, int n_in,
                              void* d_out, int out_size, void* d_ws, size_t ws_size,
                              hipStream_t stream) {
  (void)in_sizes; (void)n_in; (void)out_size; (void)ws_size;
  const float* x  = (const float*)d_in[0];
  const float* w1 = (const float*)d_in[1];
  const float* b1 = (const float*)d_in[2];
  const float* w2 = (const float*)d_in[3];
  const float* b2 = (const float*)d_in[4];
  const float* wg = (const float*)d_in[5];
  const float* bg = (const float*)d_in[6];
  float* out = (float*)d_out;
  char* ws = (char*)d_ws;

  __half* F2          = (__half*)(ws);                    // 4,718,592 B
  float* w2t          = (float*)(ws + 4718592);           // 1,048,576 B
  float* b2t          = (float*)(ws + 5767168);           //   131,072 B
  float* pooled       = (float*)(ws + 5898240);           //    18,432 B
  float* s1           = (float*)(ws + 5916672);           //    18,432 B
  unsigned char* rmap = (unsigned char*)(ws + 5935104);   //   123,008 B

  (void)hipFuncSetAttribute((const void*)k_conv3,
                            hipFuncAttributeMaxDynamicSharedMemorySize, SMEM3);

  k_prep   <<<1024, 256, 0, stream>>>(w2, b2, w2t, b2t);
  k_pool   <<<4608, 256, 0, stream>>>(x, pooled);
  k_s1     <<<18,   256, 0, stream>>>(pooled, w1, b1, s1);
  k_filters<<<1152, 256, 0, stream>>>(s1, w2t, b2t, F2);
  k_guide  <<<dim3(8, 8, 8), 256, 0, stream>>>(x, wg, bg, rmap);
  k_conv3  <<<dim3(4, 8, 8), 512, SMEM3, stream>>>(x, F2, rmap, out);
}

// Round 8
// 112.456 us; speedup vs baseline: 5.9382x; 1.0554x over previous
//
#include <hip/hip_runtime.h>
#include <hip/hip_fp16.h>
#include <math.h>

#define NPIX 15376   // 124*124

typedef _Float16 half8 __attribute__((ext_vector_type(8)));
typedef __fp16 fp16x2 __attribute__((ext_vector_type(2)));
typedef float f32x16 __attribute__((ext_vector_type(16)));

union Q2H { uint4 q; half8 h; };
union PK  { fp16x2 h; unsigned u; };
union UPK { uint2 q; _Float16 h[4]; };

// ---------------- K0: transpose w2 -> w2t[r][i][ci*64+co], b2 -> b2t[r][ci*64+co] ----
__global__ __launch_bounds__(256) void k_prep(const float* __restrict__ w2,
                                              const float* __restrict__ b2,
                                              float* __restrict__ w2t,
                                              float* __restrict__ b2t) {
  int j = blockIdx.x * 256 + threadIdx.x;        // 262,144 exact
  int co = j & 63, ci = (j >> 6) & 63, i = (j >> 12) & 7, r = j >> 15;
  w2t[j] = w2[((size_t)r * 4096 + co * 64 + ci) * 8 + i];
  if (j < 32768) {
    int co2 = j & 63, ci2 = (j >> 6) & 63, r2 = j >> 12;
    b2t[j] = b2[r2 * 4096 + co2 * 64 + ci2];
  }
}

// ---------------- K1: adaptive avg pool 126x126 -> 3x3 (42x42 blocks) ----------------
__global__ __launch_bounds__(256) void k_pool(const float* __restrict__ x,
                                              float* __restrict__ pooled) {
  int bid = blockIdx.x;
  int k = bid % 9, c = (bid / 9) & 63, b = bid / 576;
  int kh = k / 3, kw = k % 3;
  const float* xp = x + ((size_t)(b * 64 + c) * 126 + kh * 42) * 126 + kw * 42;
  float s = 0.f;
  for (int i = threadIdx.x; i < 1764; i += 256)
    s += xp[(i / 42) * 126 + (i % 42)];
  #pragma unroll
  for (int off = 32; off; off >>= 1) s += __shfl_down(s, off);
  __shared__ float red[4];
  if ((threadIdx.x & 63) == 0) red[threadIdx.x >> 6] = s;
  __syncthreads();
  if (threadIdx.x == 0)
    pooled[bid] = (red[0] + red[1] + red[2] + red[3]) * (1.f / 1764.f);
}

// ---------------- K2: s1 = sigmoid(w1 @ pooled + b1), layout [b][o][k] ----------------
__global__ __launch_bounds__(256) void k_s1(const float* __restrict__ pooled,
                                            const float* __restrict__ w1,
                                            const float* __restrict__ b1,
                                            float* __restrict__ s1) {
  int idx = blockIdx.x * 256 + threadIdx.x;
  if (idx >= 4608) return;
  int k = idx % 9, o = (idx / 9) & 63, b = idx / 576;
  const float* pp = pooled + b * 576 + k;   // stride 9 per channel
  const float* wp = w1 + o * 64;
  float acc = b1[o];
  #pragma unroll 8
  for (int c = 0; c < 64; c++) acc += pp[c * 9] * wp[c];
  s1[idx] = 1.f / (1.f + expf(-acc));
}

// ---------------- K3: filter bank in MFMA B-fragment order ---------------------------
// F2 as uint4: idx = ((b*8+r)*72 + f)*64 + lane, f = kk*8 + slice*2 + cotile.
// Lane's 8 halves e=0..7: value F(b,r, co=cotile*32+(lane&31), ci=slice*16+(lane>>5)*8+e, kk)
__global__ __launch_bounds__(256) void k_filters(const float* __restrict__ s1,
                                                 const float* __restrict__ w2t,
                                                 const float* __restrict__ b2t,
                                                 __half* __restrict__ F2) {
  int idx = blockIdx.x * 256 + threadIdx.x;   // 294,912 exact (1152 blocks)
  int lane = idx & 63;
  int f = (idx >> 6) % 72;
  int r = (idx / 4608) & 7;
  int b = idx / 36864;
  int cotile = f & 1, slice = (f >> 1) & 3, kk = f >> 3;
  int co = cotile * 32 + (lane & 31);
  int ci0 = slice * 16 + (lane >> 5) * 8;
  float sv[8];
  #pragma unroll
  for (int i = 0; i < 8; i++) sv[i] = s1[(b * 64 + r * 8 + i) * 9 + kk];
  unsigned h[8];
  #pragma unroll
  for (int e = 0; e < 8; e++) {
    int op = (ci0 + e) * 64 + co;
    float acc = b2t[r * 4096 + op];
    #pragma unroll
    for (int i = 0; i < 8; i++) acc += sv[i] * w2t[(size_t)(r * 8 + i) * 4096 + op];
    h[e] = __half_as_ushort(__float2half(acc));
  }
  uint4 q;
  q.x = h[0] | (h[1] << 16);
  q.y = h[2] | (h[3] << 16);
  q.z = h[4] | (h[5] << 16);
  q.w = h[6] | (h[7] << 16);
  ((uint4*)F2)[idx] = q;
}

// ---------------- K4: guide conv (f32) + argmax -> rmap bytes ------------------------
__global__ __launch_bounds__(256) void k_guide(const float* __restrict__ x,
                                               const float* __restrict__ wg,
                                               const float* __restrict__ bg,
                                               unsigned char* __restrict__ rmap) {
  __shared__ float wgl[4608];   // [ci][k][r]
  int t = threadIdx.x;
  for (int i = t; i < 4608; i += 256) {
    int r = i / 576, rem = i % 576;      // rem = ci*9+k
    wgl[rem * 8 + r] = wg[i];
  }
  __syncthreads();
  int tx = blockIdx.x, ty = blockIdx.y, b = blockIdx.z;
  int gx = tx * 16 + (t & 15);
  int gy = ty * 16 + (t >> 4);
  int xc = min(gx, 123);
  int yc = min(gy, 123);
  const float* xb = x + ((size_t)b * 64 * 126 + yc) * 126 + xc;
  float a0[8];
  #pragma unroll
  for (int r = 0; r < 8; r++) a0[r] = bg[r];
  for (int ci = 0; ci < 64; ci++) {
    const float* xp = xb + ci * 15876;
    const float* wp = wgl + ci * 72;
    #pragma unroll
    for (int k = 0; k < 9; k++) {
      float xv = xp[(k / 3) * 126 + (k % 3)];
      #pragma unroll
      for (int r = 0; r < 8; r++) a0[r] += xv * wp[k * 8 + r];
    }
  }
  if (gx < 124 && gy < 124) {
    int best = 0; float bv = a0[0];
    #pragma unroll
    for (int r = 1; r < 8; r++) if (a0[r] > bv) { bv = a0[r]; best = r; }
    rmap[b * NPIX + gy * 124 + gx] = (unsigned char)best;
  }
}

// ---------------- K5: MFMA region conv, paired chunks + B double-buffer --------------
// Block = 32x16 px tile, 512 threads. Work unit = (region, pair of 32-px chunks):
// 64 px share each 8-fragment B set -> 16 MFMA per 8 B-loads per tap; B for tap kk+1
// prefetched into a second register set while tap kk computes (partial vmcnt waits).
#define PATCH_U32S 19584    // 612 pix * 32 ci-pairs
#define CBUF_OFF   78336    // u32[32][514] = 65,792 B
#define LIST_OFF   144128   // u16[8*512]   =  8,192 B
#define CNT_OFF    152320   // u32[8]
#define WL_OFF     152352   // u8[40]
#define WLT_OFF    152392   // u32
#define SMEM3      152400

#define MFMA32(A, B, C) __builtin_amdgcn_mfma_f32_32x32x16_f16(A, B, C, 0, 0, 0)

#define LOADB(P, KK) { const uint4* fk = Fb + (KK) * 512;                    \
  P[0].q = fk[0];   P[1].q = fk[64];  P[2].q = fk[128]; P[3].q = fk[192];    \
  P[4].q = fk[256]; P[5].q = fk[320]; P[6].q = fk[384]; P[7].q = fk[448]; }

#define STEP(KK, B) {                                                        \
  int pxA = (prow0 + (KK) / 3) * 34 + pcol0 + (KK) % 3;                      \
  int pbA = pxA * 128, swA = (pxA & 7) << 4;                                 \
  half8 a0A = *(const half8*)(smem + pbA + ((0   + lhi * 16) ^ swA));        \
  half8 a1A = *(const half8*)(smem + pbA + ((32  + lhi * 16) ^ swA));        \
  half8 a2A = *(const half8*)(smem + pbA + ((64  + lhi * 16) ^ swA));        \
  half8 a3A = *(const half8*)(smem + pbA + ((96  + lhi * 16) ^ swA));        \
  int pxB = (prow1 + (KK) / 3) * 34 + pcol1 + (KK) % 3;                      \
  int pbB = pxB * 128, swB = (pxB & 7) << 4;                                 \
  half8 a0B = *(const half8*)(smem + pbB + ((0   + lhi * 16) ^ swB));        \
  half8 a1B = *(const half8*)(smem + pbB + ((32  + lhi * 16) ^ swB));        \
  half8 a2B = *(const half8*)(smem + pbB + ((64  + lhi * 16) ^ swB));        \
  half8 a3B = *(const half8*)(smem + pbB + ((96  + lhi * 16) ^ swB));        \
  C00 = MFMA32(a0A, B[0].h, C00); C01 = MFMA32(a0A, B[1].h, C01);            \
  C10 = MFMA32(a0B, B[0].h, C10); C11 = MFMA32(a0B, B[1].h, C11);            \
  C00 = MFMA32(a1A, B[2].h, C00); C01 = MFMA32(a1A, B[3].h, C01);            \
  C10 = MFMA32(a1B, B[2].h, C10); C11 = MFMA32(a1B, B[3].h, C11);            \
  C00 = MFMA32(a2A, B[4].h, C00); C01 = MFMA32(a2A, B[5].h, C01);            \
  C10 = MFMA32(a2B, B[4].h, C10); C11 = MFMA32(a2B, B[5].h, C11);            \
  C00 = MFMA32(a3A, B[6].h, C00); C01 = MFMA32(a3A, B[7].h, C01);            \
  C10 = MFMA32(a3B, B[6].h, C10); C11 = MFMA32(a3B, B[7].h, C11); }

__global__ __launch_bounds__(512, 2) void k_conv3(const float* __restrict__ x,
                                                  const __half* __restrict__ F2,
                                                  const unsigned char* __restrict__ rmap,
                                                  float* __restrict__ out) {
  extern __shared__ __align__(16) char smem[];
  unsigned* cbuf = (unsigned*)(smem + CBUF_OFF);
  unsigned short* list = (unsigned short*)(smem + LIST_OFF);
  unsigned* cnt = (unsigned*)(smem + CNT_OFF);
  unsigned char* wl = (unsigned char*)(smem + WL_OFF);
  unsigned* wltot = (unsigned*)(smem + WLT_OFF);

  int tx = blockIdx.x, ty = blockIdx.y, b = blockIdx.z;
  int x0 = tx * 32, y0 = ty * 16;
  int t = threadIdx.x;

  if (t < 8) cnt[t] = 0;

  // ---- stage x patch: channel-last f16, XOR-swizzled, coalesced global reads ----
  for (int e = t; e < PATCH_U32S; e += 512) {
    int ci2 = e / 612;
    int pix = e - ci2 * 612;
    int row = pix / 34, col = pix - row * 34;
    int gy = min(y0 + row, 125);
    int gx = min(x0 + col, 125);
    const float* xp = x + ((size_t)(b * 64 + ci2 * 2) * 126 + gy) * 126 + gx;
    unsigned lo = __half_as_ushort(__float2half(xp[0]));
    unsigned hi = __half_as_ushort(__float2half(xp[15876]));
    int byte = pix * 128 + ((ci2 * 4) ^ ((pix & 7) << 4));
    *(unsigned*)(smem + byte) = (hi << 16) | lo;
  }
  __syncthreads();   // patch staged, cnt zeroed

  // ---- per-region pixel lists (LDS atomics) ----
  {
    int prow = t >> 5, pcol = t & 31;
    int gy = y0 + prow, gx = x0 + pcol;
    if (gy < 124 && gx < 124) {
      int rr = rmap[b * NPIX + gy * 124 + gx];
      unsigned pos = atomicAdd(&cnt[rr], 1u);
      list[rr * 512 + pos] = (unsigned short)t;
    }
  }
  __syncthreads();

  // ---- worklist of (region, chunk-pair) units ----
  if (t == 0) {
    int tot = 0;
    for (int r = 0; r < 8; r++) {
      int nc = ((int)cnt[r] + 31) >> 5;    // 32-px chunks
      int ng = (nc + 1) >> 1;              // pairs
      for (int j = 0; j < ng; j++) wl[tot++] = (unsigned char)((r << 4) | j);
    }
    *wltot = (unsigned)tot;
  }
  __syncthreads();

  int wid = t >> 6;
  int lane = t & 63;
  int l31 = lane & 31, lhi = lane >> 5;
  int nunits = (int)*wltot;
  const uint4* F2q = (const uint4*)F2;

  for (int u = wid; u < nunits; u += 8) {
    int e = wl[u];
    int r = e >> 4, g = e & 15;
    int rcnt = (int)cnt[r];
    int s0 = g * 2, s1v = g * 2 + 1;
    int p0 = list[r * 512 + min(s0 * 32 + l31, rcnt - 1)];
    int p1 = list[r * 512 + min(s1v * 32 + l31, rcnt - 1)];
    int prow0 = p0 >> 5, pcol0 = p0 & 31;
    int prow1 = p1 >> 5, pcol1 = p1 & 31;
    const uint4* Fb = F2q + (size_t)(b * 8 + r) * 4608 + lane;

    f32x16 C00 = {0,0,0,0,0,0,0,0,0,0,0,0,0,0,0,0};
    f32x16 C01 = {0,0,0,0,0,0,0,0,0,0,0,0,0,0,0,0};
    f32x16 C10 = {0,0,0,0,0,0,0,0,0,0,0,0,0,0,0,0};
    f32x16 C11 = {0,0,0,0,0,0,0,0,0,0,0,0,0,0,0,0};

    Q2H bc[8], bn[8];

    LOADB(bc, 0);
    LOADB(bn, 1); STEP(0, bc);
    LOADB(bc, 2); STEP(1, bn);
    LOADB(bn, 3); STEP(2, bc);
    LOADB(bc, 4); STEP(3, bn);
    LOADB(bn, 5); STEP(4, bc);
    LOADB(bc, 6); STEP(5, bn);
    LOADB(bn, 7); STEP(6, bc);
    LOADB(bc, 8); STEP(7, bn);
    STEP(8, bc);

    // ---- pack (co, co+32) as f16x2 into cbuf (stride 514 -> conflict-free) ----
    #pragma unroll
    for (int reg = 0; reg < 16; reg++) {
      int row = (reg & 3) + 8 * (reg >> 2) + 4 * lhi;
      int si0 = s0 * 32 + row;
      if (si0 < rcnt) {
        int pp = list[r * 512 + si0];
        PK pk; pk.h = __builtin_amdgcn_cvt_pkrtz(C00[reg], C01[reg]);
        cbuf[l31 * 514 + pp] = pk.u;
      }
      int si1 = s1v * 32 + row;
      if (si1 < rcnt) {
        int pp = list[r * 512 + si1];
        PK pk; pk.h = __builtin_amdgcn_cvt_pkrtz(C10[reg], C11[reg]);
        cbuf[l31 * 514 + pp] = pk.u;
      }
    }
  }
  __syncthreads();   // all units done, cbuf complete

  // ---- final pass: coalesced dwordx2 stores, pixel pairs ----
  {
    int half16 = t >> 8;              // cp block: 0 -> 0..15, 1 -> 16..31
    int pe = (t & 255) * 2;           // even pixel index
    int prow = pe >> 5, pcol = pe & 31;
    int gy = y0 + prow, gx = x0 + pcol;
    if (gy < 124 && gx < 124) {       // gx even => gx+1 also valid
      float* ob = out + (size_t)b * 64 * NPIX + (size_t)gy * 124 + gx;
      #pragma unroll
      for (int j = 0; j < 16; j++) {
        int cp = half16 * 16 + j;
        UPK c;
        c.q = *(const uint2*)&cbuf[cp * 514 + pe];
        float2 s0 = { (float)c.h[0], (float)c.h[2] };   // co=cp,    px pe, pe+1
        float2 s1 = { (float)c.h[1], (float)c.h[3] };   // co=cp+32, px pe, pe+1
        *(float2*)(ob + (size_t)cp * NPIX) = s0;
        *(float2*)(ob + (size_t)(cp + 32) * NPIX) = s1;
      }
    }
  }
}

extern "C" void kernel_launch(void* const* d_in, const int* in_sizes, int n_in,
                              void* d_out, int out_size, void* d_ws, size_t ws_size,
                              hipStream_t stream) {
  (void)in_sizes; (void)n_in; (void)out_size; (void)ws_size;
  const float* x  = (const float*)d_in[0];
  const float* w1 = (const float*)d_in[1];
  const float* b1 = (const float*)d_in[2];
  const float* w2 = (const float*)d_in[3];
  const float* b2 = (const float*)d_in[4];
  const float* wg = (const float*)d_in[5];
  const float* bg = (const float*)d_in[6];
  float* out = (float*)d_out;
  char* ws = (char*)d_ws;

  __half* F2          = (__half*)(ws);                    // 4,718,592 B
  float* w2t          = (float*)(ws + 4718592);           // 1,048,576 B
  float* b2t          = (float*)(ws + 5767168);           //   131,072 B
  float* pooled       = (float*)(ws + 5898240);           //    18,432 B
  float* s1           = (float*)(ws + 5916672);           //    18,432 B
  unsigned char* rmap = (unsigned char*)(ws + 5935104);   //   123,008 B

  (void)hipFuncSetAttribute((const void*)k_conv3,
                            hipFuncAttributeMaxDynamicSharedMemorySize, SMEM3);

  k_prep   <<<1024, 256, 0, stream>>>(w2, b2, w2t, b2t);
  k_pool   <<<4608, 256, 0, stream>>>(x, pooled);
  k_s1     <<<18,   256, 0, stream>>>(pooled, w1, b1, s1);
  k_filters<<<1152, 256, 0, stream>>>(s1, w2t, b2t, F2);
  k_guide  <<<dim3(8, 8, 8), 256, 0, stream>>>(x, wg, bg, rmap);
  k_conv3  <<<dim3(4, 8, 8), 512, SMEM3, stream>>>(x, F2, rmap, out);
}

// Round 9
// 108.840 us; speedup vs baseline: 6.1355x; 1.0332x over previous
//
#include <hip/hip_runtime.h>
#include <hip/hip_fp16.h>
#include <math.h>

#define NPIX 15376   // 124*124

typedef _Float16 half8 __attribute__((ext_vector_type(8)));
typedef __fp16 fp16x2 __attribute__((ext_vector_type(2)));
typedef float f32x16 __attribute__((ext_vector_type(16)));

union Q2H { uint4 q; half8 h; };
union PK  { fp16x2 h; unsigned u; };
union UPK { uint2 q; _Float16 h[4]; };

// ---------------- K1: adaptive avg pool 126x126 -> 3x3 (42x42 blocks) ----------------
__global__ __launch_bounds__(256) void k_pool(const float* __restrict__ x,
                                              float* __restrict__ pooled) {
  int bid = blockIdx.x;
  int k = bid % 9, c = (bid / 9) & 63, b = bid / 576;
  int kh = k / 3, kw = k % 3;
  const float* xp = x + ((size_t)(b * 64 + c) * 126 + kh * 42) * 126 + kw * 42;
  float s = 0.f;
  for (int i = threadIdx.x; i < 1764; i += 256)
    s += xp[(i / 42) * 126 + (i % 42)];
  #pragma unroll
  for (int off = 32; off; off >>= 1) s += __shfl_down(s, off);
  __shared__ float red[4];
  if ((threadIdx.x & 63) == 0) red[threadIdx.x >> 6] = s;
  __syncthreads();
  if (threadIdx.x == 0)
    pooled[bid] = (red[0] + red[1] + red[2] + red[3]) * (1.f / 1764.f);
}

// ---------------- K2: s1 = sigmoid(w1 @ pooled + b1), layout [b][o][k] ----------------
__global__ __launch_bounds__(256) void k_s1(const float* __restrict__ pooled,
                                            const float* __restrict__ w1,
                                            const float* __restrict__ b1,
                                            float* __restrict__ s1) {
  int idx = blockIdx.x * 256 + threadIdx.x;
  if (idx >= 4608) return;
  int k = idx % 9, o = (idx / 9) & 63, b = idx / 576;
  const float* pp = pooled + b * 576 + k;   // stride 9 per channel
  const float* wp = w1 + o * 64;
  float acc = b1[o];
  #pragma unroll 8
  for (int c = 0; c < 64; c++) acc += pp[c * 9] * wp[c];
  s1[idx] = 1.f / (1.f + expf(-acc));
}

// ---------------- K3: filter bank in MFMA B-fragment order (reads w2/b2 direct) ------
// F2 as uint4: idx = ((b*8+r)*72 + f)*64 + lane, f = kk*8 + slice*2 + cotile.
// Lane's 8 halves e: F(b,r, co=cotile*32+(lane&31), ci=slice*16+(lane>>5)*8+e, kk)
// F = b2[r][co*64+ci] + sum_i s1[b][r*8+i][k] * w2[r][co*64+ci][i]
__global__ __launch_bounds__(256) void k_filters(const float* __restrict__ s1,
                                                 const float* __restrict__ w2,
                                                 const float* __restrict__ b2,
                                                 __half* __restrict__ F2) {
  int idx = blockIdx.x * 256 + threadIdx.x;   // 294,912 exact (1152 blocks)
  int lane = idx & 63;
  int f = (idx >> 6) % 72;
  int r = (idx / 4608) & 7;
  int b = idx / 36864;
  int cotile = f & 1, slice = (f >> 1) & 3, kk = f >> 3;
  int co = cotile * 32 + (lane & 31);
  int ci0 = slice * 16 + (lane >> 5) * 8;
  float sv[8];
  #pragma unroll
  for (int i = 0; i < 8; i++) sv[i] = s1[(b * 64 + r * 8 + i) * 9 + kk];
  unsigned h[8];
  #pragma unroll
  for (int e = 0; e < 8; e++) {
    int o = co * 64 + (ci0 + e);
    float acc = b2[r * 4096 + o];
    const float* wp = w2 + (size_t)(r * 4096 + o) * 8;
    #pragma unroll
    for (int i = 0; i < 8; i++) acc += sv[i] * wp[i];
    h[e] = __half_as_ushort(__float2half(acc));
  }
  uint4 q;
  q.x = h[0] | (h[1] << 16);
  q.y = h[2] | (h[3] << 16);
  q.z = h[4] | (h[5] << 16);
  q.w = h[6] | (h[7] << 16);
  ((uint4*)F2)[idx] = q;
}

// ---------------- K4: fused guide + MFMA region conv, 16x16 tiles, 2 blocks/CU -------
// 256 threads. LDS: patch f16 channel-last XOR-swizzled [324px][128B] (41,472) +
// cbuf u32[32][258] (33,024; its first 18,432B double as wgl f32[4608] during the
// guide phase, dead before any cbuf write) + lists u16[8][256] + cnt/wl.
#define PATCH_BYTES 41472
#define WGL_OFF     41472
#define CBUF_OFF    41472
#define LIST_OFF    74496
#define CNT_OFF     78592
#define WL_OFF      78624
#define WLT_OFF     78668
#define SMEM4       78672

#define MFMA32(A, B, C) __builtin_amdgcn_mfma_f32_32x32x16_f16(A, B, C, 0, 0, 0)

#define LOADB(P, KK) { const uint4* fk = Fb + (KK) * 512;                    \
  P[0].q = fk[0];   P[1].q = fk[64];  P[2].q = fk[128]; P[3].q = fk[192];    \
  P[4].q = fk[256]; P[5].q = fk[320]; P[6].q = fk[384]; P[7].q = fk[448]; }

#define STEP(KK, B) {                                                        \
  int pxA = (prow0 + (KK) / 3) * 18 + pcol0 + (KK) % 3;                      \
  int pbA = pxA * 128, swA = (pxA & 7) << 4;                                 \
  half8 a0A = *(const half8*)(smem + pbA + ((0   + lhi * 16) ^ swA));        \
  half8 a1A = *(const half8*)(smem + pbA + ((32  + lhi * 16) ^ swA));        \
  half8 a2A = *(const half8*)(smem + pbA + ((64  + lhi * 16) ^ swA));        \
  half8 a3A = *(const half8*)(smem + pbA + ((96  + lhi * 16) ^ swA));        \
  int pxB = (prow1 + (KK) / 3) * 18 + pcol1 + (KK) % 3;                      \
  int pbB = pxB * 128, swB = (pxB & 7) << 4;                                 \
  half8 a0B = *(const half8*)(smem + pbB + ((0   + lhi * 16) ^ swB));        \
  half8 a1B = *(const half8*)(smem + pbB + ((32  + lhi * 16) ^ swB));        \
  half8 a2B = *(const half8*)(smem + pbB + ((64  + lhi * 16) ^ swB));        \
  half8 a3B = *(const half8*)(smem + pbB + ((96  + lhi * 16) ^ swB));        \
  C00 = MFMA32(a0A, B[0].h, C00); C01 = MFMA32(a0A, B[1].h, C01);            \
  C10 = MFMA32(a0B, B[0].h, C10); C11 = MFMA32(a0B, B[1].h, C11);            \
  C00 = MFMA32(a1A, B[2].h, C00); C01 = MFMA32(a1A, B[3].h, C01);            \
  C10 = MFMA32(a1B, B[2].h, C10); C11 = MFMA32(a1B, B[3].h, C11);            \
  C00 = MFMA32(a2A, B[4].h, C00); C01 = MFMA32(a2A, B[5].h, C01);            \
  C10 = MFMA32(a2B, B[4].h, C10); C11 = MFMA32(a2B, B[5].h, C11);            \
  C00 = MFMA32(a3A, B[6].h, C00); C01 = MFMA32(a3A, B[7].h, C01);            \
  C10 = MFMA32(a3B, B[6].h, C10); C11 = MFMA32(a3B, B[7].h, C11); }

__global__ __launch_bounds__(256, 2) void k_conv4(const float* __restrict__ x,
                                                  const __half* __restrict__ F2,
                                                  const float* __restrict__ wg,
                                                  const float* __restrict__ bg,
                                                  float* __restrict__ out) {
  extern __shared__ __align__(16) char smem[];
  float* wgl = (float*)(smem + WGL_OFF);
  unsigned* cbuf = (unsigned*)(smem + CBUF_OFF);
  unsigned short* list = (unsigned short*)(smem + LIST_OFF);
  unsigned* cnt = (unsigned*)(smem + CNT_OFF);
  unsigned char* wl = (unsigned char*)(smem + WL_OFF);
  unsigned* wltot = (unsigned*)(smem + WLT_OFF);

  int tx = blockIdx.x, ty = blockIdx.y, b = blockIdx.z;
  int x0 = tx * 16, y0 = ty * 16;
  int t = threadIdx.x;

  if (t < 8) cnt[t] = 0;

  // ---- stage wgl: [ci][k][r] f32 (lives in cbuf region, dead before pack) ----
  for (int i = t; i < 4608; i += 256) {
    int r = i / 576, rem = i % 576;      // rem = ci*9+k
    wgl[rem * 8 + r] = wg[i];
  }

  // ---- stage x patch: channel-last f16, XOR-swizzled ----
  for (int p = t; p < 324; p += 256) {
    int row = p / 18, col = p - row * 18;
    int gy = min(y0 + row, 125);
    int gx = min(x0 + col, 125);
    const float* xp = x + ((size_t)(b * 64) * 126 + gy) * 126 + gx;
    int pb = p * 128;
    int sw = (p & 7) << 4;
    #pragma unroll 8
    for (int ci2 = 0; ci2 < 32; ci2++) {
      float lo = xp[(size_t)(2 * ci2) * 15876];
      float hi = xp[(size_t)(2 * ci2 + 1) * 15876];
      PK pk; pk.h = __builtin_amdgcn_cvt_pkrtz(lo, hi);
      *(unsigned*)(smem + pb + ((ci2 * 4) ^ sw)) = pk.u;
    }
  }
  __syncthreads();   // wgl + cnt ready

  // ---- guide conv (f32, from global x; same math/order as reference path) ----
  int prowT = t >> 4, pcolT = t & 15;
  int gyT = y0 + prowT, gxT = x0 + pcolT;
  bool valid = (gyT < 124) && (gxT < 124);
  int yc = min(gyT, 123), xc = min(gxT, 123);
  float a0[8];
  #pragma unroll
  for (int r = 0; r < 8; r++) a0[r] = bg[r];
  for (int ci = 0; ci < 64; ci++) {
    const float* xp = x + ((size_t)(b * 64 + ci) * 126 + yc) * 126 + xc;
    const float4* wp4 = (const float4*)(wgl + ci * 72);
    #pragma unroll
    for (int k = 0; k < 9; k++) {
      float xv = xp[(k / 3) * 126 + (k % 3)];
      float4 wA = wp4[k * 2], wB = wp4[k * 2 + 1];
      a0[0] = fmaf(xv, wA.x, a0[0]); a0[1] = fmaf(xv, wA.y, a0[1]);
      a0[2] = fmaf(xv, wA.z, a0[2]); a0[3] = fmaf(xv, wA.w, a0[3]);
      a0[4] = fmaf(xv, wB.x, a0[4]); a0[5] = fmaf(xv, wB.y, a0[5]);
      a0[6] = fmaf(xv, wB.z, a0[6]); a0[7] = fmaf(xv, wB.w, a0[7]);
    }
  }
  // argmax (first-max, matches jnp.argmax) + list append
  if (valid) {
    int best = 0; float bv = a0[0];
    #pragma unroll
    for (int r = 1; r < 8; r++) if (a0[r] > bv) { bv = a0[r]; best = r; }
    unsigned pos = atomicAdd(&cnt[best], 1u);
    list[best * 256 + pos] = (unsigned short)t;
  }
  __syncthreads();

  // ---- worklist of (region, chunk-pair) units ----
  if (t == 0) {
    int tot = 0;
    for (int r = 0; r < 8; r++) {
      int nc = ((int)cnt[r] + 31) >> 5;    // 32-px chunks
      int ng = (nc + 1) >> 1;              // pairs
      for (int j = 0; j < ng; j++) wl[tot++] = (unsigned char)((r << 4) | j);
    }
    *wltot = (unsigned)tot;
  }
  __syncthreads();

  int wid = t >> 6;        // 0..3
  int lane = t & 63;
  int l31 = lane & 31, lhi = lane >> 5;
  int nunits = (int)*wltot;
  const uint4* F2q = (const uint4*)F2;

  for (int u = wid; u < nunits; u += 4) {
    int e = wl[u];
    int r = e >> 4, g = e & 15;
    int rcnt = (int)cnt[r];
    int s0 = g * 2, s1v = g * 2 + 1;
    int p0 = list[r * 256 + min(s0 * 32 + l31, rcnt - 1)];
    int p1 = list[r * 256 + min(s1v * 32 + l31, rcnt - 1)];
    int prow0 = p0 >> 4, pcol0 = p0 & 15;
    int prow1 = p1 >> 4, pcol1 = p1 & 15;
    const uint4* Fb = F2q + (size_t)(b * 8 + r) * 4608 + lane;

    f32x16 C00 = {0,0,0,0,0,0,0,0,0,0,0,0,0,0,0,0};
    f32x16 C01 = {0,0,0,0,0,0,0,0,0,0,0,0,0,0,0,0};
    f32x16 C10 = {0,0,0,0,0,0,0,0,0,0,0,0,0,0,0,0};
    f32x16 C11 = {0,0,0,0,0,0,0,0,0,0,0,0,0,0,0,0};

    Q2H bc[8], bn[8];

    LOADB(bc, 0);
    LOADB(bn, 1); STEP(0, bc);
    LOADB(bc, 2); STEP(1, bn);
    LOADB(bn, 3); STEP(2, bc);
    LOADB(bc, 4); STEP(3, bn);
    LOADB(bn, 5); STEP(4, bc);
    LOADB(bc, 6); STEP(5, bn);
    LOADB(bn, 7); STEP(6, bc);
    LOADB(bc, 8); STEP(7, bn);
    STEP(8, bc);

    // ---- pack (co, co+32) as f16x2 into cbuf (wgl is dead by now) ----
    #pragma unroll
    for (int reg = 0; reg < 16; reg++) {
      int row = (reg & 3) + 8 * (reg >> 2) + 4 * lhi;
      int si0 = s0 * 32 + row;
      if (si0 < rcnt) {
        int pp = list[r * 256 + si0];
        PK pk; pk.h = __builtin_amdgcn_cvt_pkrtz(C00[reg], C01[reg]);
        cbuf[l31 * 258 + pp] = pk.u;
      }
      int si1 = s1v * 32 + row;
      if (si1 < rcnt) {
        int pp = list[r * 256 + si1];
        PK pk; pk.h = __builtin_amdgcn_cvt_pkrtz(C10[reg], C11[reg]);
        cbuf[l31 * 258 + pp] = pk.u;
      }
    }
  }
  __syncthreads();   // all units done, cbuf complete

  // ---- final pass: coalesced dwordx2 stores, pixel pairs ----
  {
    int half16 = t >> 7;              // cp block: 0 -> 0..15, 1 -> 16..31
    int pe = (t & 127) * 2;           // even pixel index (0..254)
    int prow = pe >> 4, pcol = pe & 15;
    int gy = y0 + prow, gx = x0 + pcol;
    if (gy < 124 && gx < 124) {       // gx even => gx+1 also valid
      float* ob = out + (size_t)b * 64 * NPIX + (size_t)gy * 124 + gx;
      #pragma unroll
      for (int j = 0; j < 16; j++) {
        int cp = half16 * 16 + j;
        UPK c;
        c.q = *(const uint2*)&cbuf[cp * 258 + pe];
        float2 v0 = { (float)c.h[0], (float)c.h[2] };   // co=cp,    px pe, pe+1
        float2 v1 = { (float)c.h[1], (float)c.h[3] };   // co=cp+32, px pe, pe+1
        *(float2*)(ob + (size_t)cp * NPIX) = v0;
        *(float2*)(ob + (size_t)(cp + 32) * NPIX) = v1;
      }
    }
  }
}

extern "C" void kernel_launch(void* const* d_in, const int* in_sizes, int n_in,
                              void* d_out, int out_size, void* d_ws, size_t ws_size,
                              hipStream_t stream) {
  (void)in_sizes; (void)n_in; (void)out_size; (void)ws_size;
  const float* x  = (const float*)d_in[0];
  const float* w1 = (const float*)d_in[1];
  const float* b1 = (const float*)d_in[2];
  const float* w2 = (const float*)d_in[3];
  const float* b2 = (const float*)d_in[4];
  const float* wg = (const float*)d_in[5];
  const float* bg = (const float*)d_in[6];
  float* out = (float*)d_out;
  char* ws = (char*)d_ws;

  __half* F2    = (__half*)(ws);               // 4,718,592 B
  float* pooled = (float*)(ws + 4718592);      //    18,432 B
  float* s1     = (float*)(ws + 4737024);      //    18,432 B

  (void)hipFuncSetAttribute((const void*)k_conv4,
                            hipFuncAttributeMaxDynamicSharedMemorySize, SMEM4);

  k_pool   <<<4608, 256, 0, stream>>>(x, pooled);
  k_s1     <<<18,   256, 0, stream>>>(pooled, w1, b1, s1);
  k_filters<<<1152, 256, 0, stream>>>(s1, w2, b2, F2);
  k_conv4  <<<dim3(8, 8, 8), 256, SMEM4, stream>>>(x, F2, wg, bg, out);
}